// Round 5
// baseline (1480.381 us; speedup 1.0000x reference)
//
#include <hip/hip_runtime.h>
#include <hip/hip_bf16.h>
#include <math.h>

#define NB 32
#define CH 16
#define N1 127
#define G 256
#define GG (G*G)

// ---------------------------------------------------------------------------
__global__ void init_sintab(float* __restrict__ sintab) {
    int t = threadIdx.x;
    sintab[t] = sinf(6.28318530717958647692f * (float)t / 256.0f);
}

// adj(w)[b,a,c,ky,kx] = conj(w[b,c,a,kx,ky])
__global__ __launch_bounds__(256) void prep_adj16(
    const float* __restrict__ wr, const float* __restrict__ wi,
    float* __restrict__ our, float* __restrict__ oui) {
    int idx = blockIdx.x * 256 + threadIdx.x;
    if (idx >= NB*CH*CH*9) return;
    int tap = idx % 9; int t = idx / 9;
    int c = t % CH; t /= CH;
    int a = t % CH; int b = t / CH;
    int ky = tap / 3, kx = tap % 3;
    int src = ((b*CH + c)*CH + a)*9 + kx*3 + ky;
    our[idx] = wr[src];
    oui[idx] = -wi[src];
}

__global__ __launch_bounds__(256) void prep_adj1(
    const float* __restrict__ wr, const float* __restrict__ wi,
    float* __restrict__ our, float* __restrict__ oui) {
    int idx = blockIdx.x * 256 + threadIdx.x;
    if (idx >= NB*CH*9) return;
    int tap = idx % 9; int t = idx / 9;
    int c = t % CH; int b = t / CH;
    int ky = tap / 3, kx = tap % 3;
    int src = (b*CH + c)*9 + kx*3 + ky;
    our[idx] = wr[src];
    oui[idx] = -wi[src];
}

// ---------------------------------------------------------------------------
// Kernel-tap composition: R[t] = sum_{a+b=t} P[a] Q[b]  (complex), contract CM
template<int CO, int CM, int CI, int KP, int KQ>
__global__ __launch_bounds__(256) void compose_k(
    const float* __restrict__ Pr, const float* __restrict__ Pi,
    const float* __restrict__ Qr, const float* __restrict__ Qi,
    float* __restrict__ Rr, float* __restrict__ Ri) {
    constexpr int T = KP + KQ - 1;
    int idx = blockIdx.x * 256 + threadIdx.x;
    if (idx >= NB*CO*CI*T*T) return;
    int txp = idx % T; int t = idx / T;
    int typ = t % T; t /= T;
    int ci = t % CI; t /= CI;
    int co = t % CO; int b = t / CO;
    float ar = 0.f, ai = 0.f;
    for (int m = 0; m < CM; ++m) {
        const float* pr = Pr + (((size_t)b*CO + co)*CM + m)*KP*KP;
        const float* pi = Pi + (((size_t)b*CO + co)*CM + m)*KP*KP;
        const float* qr = Qr + (((size_t)b*CM + m)*CI + ci)*KQ*KQ;
        const float* qi = Qi + (((size_t)b*CM + m)*CI + ci)*KQ*KQ;
        for (int ay = 0; ay < KP; ++ay) {
            int by = typ - ay; if (by < 0 || by >= KQ) continue;
            for (int ax = 0; ax < KP; ++ax) {
                int bx = txp - ax; if (bx < 0 || bx >= KQ) continue;
                float prr = pr[ay*KP+ax], pii = pi[ay*KP+ax];
                float qrr = qr[by*KQ+bx], qii = qi[by*KQ+bx];
                ar += prr*qrr - pii*qii;
                ai += prr*qii + pii*qrr;
            }
        }
    }
    Rr[idx] = ar; Ri[idx] = ai;
}

// ---------------------------------------------------------------------------
// DST stage 1
__global__ __launch_bounds__(256) void dst_stage1(
    const float* __restrict__ r, const float* __restrict__ sintab,
    float* __restrict__ T1, int nb) {
    __shared__ float ss[256];
    ss[threadIdx.x] = sintab[threadIdx.x];
    __syncthreads();
    int idx = blockIdx.x * 256 + threadIdx.x;
    if (idx >= nb*G*N1) return;
    int kk = idx % N1;
    int t = idx / N1;
    int j1 = t & 255; int b = t >> 8;
    const float* rb = r + b * N1 * N1;
    float acc = 0.f;
    for (int K = 1; K <= N1; ++K) {
        float s = ss[(j1 * K) & 255];
        float v = rb[(K - 1) * N1 + kk];
        acc += (K & 1) ? -s * v : s * v;
    }
    T1[idx] = acc;
}

// DST stage 2
__global__ __launch_bounds__(256) void dst_stage2(
    const float* __restrict__ T1, const float* __restrict__ sintab,
    float* __restrict__ rhat) {
    __shared__ float ss[256];
    ss[threadIdx.x] = sintab[threadIdx.x];
    __syncthreads();
    int idx = blockIdx.x * 256 + threadIdx.x;
    int j2 = idx & 255;
    int t = idx >> 8;
    int j1 = t & 255; int b = t >> 8;
    const float* t1 = T1 + ((size_t)b * G + j1) * N1;
    float acc = 0.f;
    for (int kk = 0; kk < N1; ++kk) {
        float s = ss[(j2 * (kk + 1)) & 255];
        float v = t1[kk];
        acc += ((kk + 1) & 1) ? -s * v : s * v;
    }
    rhat[idx] = acc * (-4.0f / 65536.0f);
}

// ---------------------------------------------------------------------------
// Forward composed 7x7 conv: rhat (real, 1ch) -> A (16ch complex)
__global__ __launch_bounds__(256) void fwd7_kernel(
    const float* __restrict__ rhat,
    const float* __restrict__ w7r, const float* __restrict__ w7i, // [b][16][49]
    float* __restrict__ yr, float* __restrict__ yi) {
    __shared__ float sW[16*49*2];
    __shared__ float sIn[22*38];
    const int b = blockIdx.y;
    const int tile = blockIdx.x;            // 8 x-tiles (32) x 16 y-tiles (16)
    const int x0 = (tile & 7) * 32;
    const int y0 = (tile >> 3) * 16;
    const int tid = threadIdx.x;
    const float* wrb = w7r + (size_t)b * 784;
    const float* wib = w7i + (size_t)b * 784;
    for (int t = tid; t < 784; t += 256) { sW[2*t] = wrb[t]; sW[2*t+1] = wib[t]; }
    const float* rb = rhat + (size_t)b * GG;
    for (int t = tid; t < 22*38; t += 256) {
        int rr = t / 38, cc = t - rr * 38;
        int gy = y0 + rr - 3, gx = x0 + cc - 3;
        bool ok = ((unsigned)gy < G) & ((unsigned)gx < G);
        sIn[t] = ok ? rb[gy * G + gx] : 0.f;
    }
    __syncthreads();
    const int tx = tid & 31;
    const int ty = tid >> 5;    // 0..7
    float accR[2][16], accI[2][16];
#pragma unroll
    for (int p = 0; p < 2; ++p)
#pragma unroll
        for (int co = 0; co < 16; ++co) { accR[p][co] = 0.f; accI[p][co] = 0.f; }
#pragma unroll
    for (int tap = 0; tap < 49; ++tap) {
        const int dy = tap / 7, dx = tap % 7;
        float x0v = sIn[(ty + dy) * 38 + tx + dx];
        float x1v = sIn[(ty + 8 + dy) * 38 + tx + dx];
#pragma unroll
        for (int co = 0; co < 16; ++co) {
            const float2 wv = *reinterpret_cast<const float2*>(&sW[(co*49 + tap)*2]);
            accR[0][co] += x0v * wv.x; accI[0][co] += x0v * wv.y;
            accR[1][co] += x1v * wv.x; accI[1][co] += x1v * wv.y;
        }
    }
    const size_t outB = (size_t)b * 16 * GG;
#pragma unroll
    for (int co = 0; co < 16; ++co)
#pragma unroll
        for (int p = 0; p < 2; ++p) {
            int oy = y0 + ty + p * 8, ox = x0 + tx;
            yr[outB + (size_t)co * GG + oy * G + ox] = accR[p][co];
            yi[outB + (size_t)co * GG + oy * G + ox] = accI[p][co];
        }
}

// ---------------------------------------------------------------------------
// Adjoint composed 7x7 conv with fused theta: (A .* theta) (16ch) -> HC (1ch).
// Sliding-window register reuse: each thread owns 8 consecutive-x outputs in
// one row. Per (ci,dy): 14 b64 input reads + 7 weight broadcasts serve 224 FMA.
// Also extracts the 5-wide border bands of theta.*A into packed PTA
// [b][ci][s:4][pu:5][v:256][2] for the strip correction.
__global__ __launch_bounds__(256, 2) void adj7_kernel(
    const float* __restrict__ xr, const float* __restrict__ xi,
    const float* __restrict__ tr, const float* __restrict__ ti,
    const float* __restrict__ w7r, const float* __restrict__ w7i, // [b][16][49]
    float* __restrict__ or_, float* __restrict__ oi_,
    float* __restrict__ PTA) {
    __shared__ float sW[16*49*2];
    __shared__ float sIn[38*70*2];
    const int b = blockIdx.y;
    const int tile = blockIdx.x;            // 4 x-tiles (64) x 8 y-tiles (32)
    const int x0 = (tile & 3) * 64;
    const int y0 = (tile >> 2) * 32;
    const int tid = threadIdx.x;
    const float* wrb = w7r + (size_t)b * 784;
    const float* wib = w7i + (size_t)b * 784;
    for (int t = tid; t < 784; t += 256) { sW[2*t] = wrb[t]; sW[2*t+1] = wib[t]; }
    const int ty  = tid >> 3;               // 0..31 output row in tile
    const int txi = tid & 7;                // col-group: outputs x = txi*8 .. txi*8+7
    float accR[8], accI[8];
#pragma unroll
    for (int k = 0; k < 8; ++k) { accR[k] = 0.f; accI[k] = 0.f; }
    const size_t planeB = (size_t)b * 16 * GG;
    for (int ci = 0; ci < 16; ++ci) {
        __syncthreads();
        const float* xrc = xr + planeB + (size_t)ci * GG;
        const float* xic = xi + planeB + (size_t)ci * GG;
        const float* trc = tr + planeB + (size_t)ci * GG;
        const float* tic = ti + planeB + (size_t)ci * GG;
        for (int t = tid; t < 38*70; t += 256) {
            int rr = t / 70, cc = t - rr * 70;
            int gy = y0 + rr - 3, gx = x0 + cc - 3;
            float hr = 0.f, hi = 0.f;
            if (((unsigned)gy < G) & ((unsigned)gx < G)) {
                float ar = xrc[gy*G+gx], ai = xic[gy*G+gx];
                float cr = trc[gy*G+gx], cii = tic[gy*G+gx];
                hr = ar*cr - ai*cii;
                hi = ar*cii + ai*cr;
                // band extraction (duplicate same-value writes are benign)
                const size_t cbase = ((size_t)b*16 + ci) * 4;
                if (gy < 5)    { size_t o = ((cbase + 0)*5 + gy      )*256 + gx; PTA[2*o] = hr; PTA[2*o+1] = hi; }
                if (gy >= 251) { size_t o = ((cbase + 1)*5 + gy - 251)*256 + gx; PTA[2*o] = hr; PTA[2*o+1] = hi; }
                if (gx < 5)    { size_t o = ((cbase + 2)*5 + gx      )*256 + gy; PTA[2*o] = hr; PTA[2*o+1] = hi; }
                if (gx >= 251) { size_t o = ((cbase + 3)*5 + gx - 251)*256 + gy; PTA[2*o] = hr; PTA[2*o+1] = hi; }
            }
            sIn[2*t] = hr; sIn[2*t+1] = hi;
        }
        __syncthreads();
        const float* wci = &sW[ci*49*2];
#pragma unroll
        for (int dy = 0; dy < 7; ++dy) {
            float2 w[7];
#pragma unroll
            for (int dx = 0; dx < 7; ++dx)
                w[dx] = *reinterpret_cast<const float2*>(&wci[(dy*7+dx)*2]);
            float2 in[14];
            const float* rowp = &sIn[((ty + dy) * 70 + txi * 8) * 2];
#pragma unroll
            for (int j = 0; j < 14; ++j)
                in[j] = *reinterpret_cast<const float2*>(&rowp[2*j]);
#pragma unroll
            for (int dx = 0; dx < 7; ++dx)
#pragma unroll
                for (int k = 0; k < 8; ++k) {
                    accR[k] += in[k+dx].x * w[dx].x - in[k+dx].y * w[dx].y;
                    accI[k] += in[k+dx].x * w[dx].y + in[k+dx].y * w[dx].x;
                }
        }
    }
    const size_t outB = (size_t)b * GG;
    const int oy = y0 + ty, ox = x0 + txi * 8;
    float4 r0 = make_float4(accR[0], accR[1], accR[2], accR[3]);
    float4 r1 = make_float4(accR[4], accR[5], accR[6], accR[7]);
    float4 i0 = make_float4(accI[0], accI[1], accI[2], accI[3]);
    float4 i1 = make_float4(accI[4], accI[5], accI[6], accI[7]);
    *reinterpret_cast<float4*>(&or_[outB + oy*G + ox])     = r0;
    *reinterpret_cast<float4*>(&or_[outB + oy*G + ox + 4]) = r1;
    *reinterpret_cast<float4*>(&oi_[outB + oy*G + ox])     = i0;
    *reinterpret_cast<float4*>(&oi_[outB + oy*G + ox + 4]) = i1;
}

// ---------------------------------------------------------------------------
// Strip machinery. strip s: 0=TOP(rows 0..3), 1=BOT(rows 252..255),
// 2=LEF(cols 0..3), 3=RIG(cols 252..255). Packed [b][ch][s][u:4][v:256].
__device__ __forceinline__ size_t sidx(int b, int ch, int s, int u, int v) {
    return ((((size_t)b*CH + ch)*4 + s)*4 + u)*256 + v;
}
__device__ __forceinline__ void spos(int s, int u, int v, int& y, int& x) {
    y = (s == 0) ? u : (s == 1) ? 252 + u : v;
    x = (s == 2) ? u : (s == 3) ? 252 + u : v;
}

// stage 1 fwd: conv1 (w1, 1->16, real rhat) exact, all u in [0,4)
__global__ __launch_bounds__(256) void strip_fwd1(
    const float* __restrict__ rhat,
    const float* __restrict__ w1r_, const float* __restrict__ w1i_, // [b][16][9]
    float* __restrict__ S1r, float* __restrict__ S1i) {
    __shared__ float sW[16*9*2];
    const int s = blockIdx.x, b = blockIdx.y;
    for (int t = threadIdx.x; t < 144; t += 256) {
        sW[2*t] = w1r_[(size_t)b*144 + t]; sW[2*t+1] = w1i_[(size_t)b*144 + t];
    }
    __syncthreads();
    const int v = threadIdx.x;
    const float* rb = rhat + (size_t)b * GG;
    for (int u = 0; u < 4; ++u) {
        int y, x; spos(s, u, v, y, x);
        float xv[9];
#pragma unroll
        for (int dy = -1; dy <= 1; ++dy)
#pragma unroll
            for (int dx = -1; dx <= 1; ++dx) {
                int gy = y + dy, gx = x + dx;
                bool ok = ((unsigned)gy < G) & ((unsigned)gx < G);
                xv[(dy+1)*3 + dx+1] = ok ? rb[gy*G+gx] : 0.f;
            }
#pragma unroll
        for (int co = 0; co < 16; ++co) {
            float ar = 0.f, ai = 0.f;
#pragma unroll
            for (int tap = 0; tap < 9; ++tap) {
                ar += xv[tap] * sW[(co*9+tap)*2];
                ai += xv[tap] * sW[(co*9+tap)*2+1];
            }
            S1r[sidx(b, co, s, u, v)] = ar;
            S1i[sidx(b, co, s, u, v)] = ai;
        }
    }
}

// stage 1 adj (packed): a3-conv on packed theta.*A bands. u in [0,4).
// grid (16, cb): blockIdx.x = s*4 + vtile; threads 256 = 64v x 4u.
__global__ __launch_bounds__(256) void strip_adj1_packed(
    const float* __restrict__ PTA,   // [b][ci][4][5][256][2]
    const float* __restrict__ wr_, const float* __restrict__ wi_, // [b][16][16][9]
    float* __restrict__ S1r, float* __restrict__ S1i) {
    __shared__ float sW[16*16*9*2];
    const int s = blockIdx.x >> 2, vt = blockIdx.x & 3, b = blockIdx.y;
    for (int t = threadIdx.x; t < 2304; t += 256) {
        sW[2*t] = wr_[(size_t)b*2304 + t]; sW[2*t+1] = wi_[(size_t)b*2304 + t];
    }
    __syncthreads();
    const int v = vt * 64 + (threadIdx.x & 63);
    const int u = threadIdx.x >> 6;           // 0..3
    const int off = (s == 1 || s == 3) ? 1 : 0;
    float accR[16], accI[16];
#pragma unroll
    for (int co = 0; co < 16; ++co) { accR[co] = 0.f; accI[co] = 0.f; }
    for (int ci = 0; ci < 16; ++ci) {
        const float* base = PTA + ((((size_t)b*16 + ci)*4 + s)*5) * 512;
        float nR[9], nI[9];
#pragma unroll
        for (int dy = -1; dy <= 1; ++dy)
#pragma unroll
            for (int dx = -1; dx <= 1; ++dx) {
                int pu = (s < 2) ? (u + off + dy) : (u + off + dx);
                int vp = (s < 2) ? (v + dx) : (v + dy);
                float vr = 0.f, vi = 0.f;
                if (((unsigned)pu < 5u) & ((unsigned)vp < 256u)) {
                    const float2 pv = *reinterpret_cast<const float2*>(&base[(pu*256 + vp)*2]);
                    vr = pv.x; vi = pv.y;
                }
                nR[(dy+1)*3+dx+1] = vr; nI[(dy+1)*3+dx+1] = vi;
            }
#pragma unroll
        for (int co = 0; co < 16; ++co)
#pragma unroll
            for (int tap = 0; tap < 9; ++tap) {
                float wre = sW[((co*16+ci)*9+tap)*2];
                float wim = sW[((co*16+ci)*9+tap)*2+1];
                accR[co] += nR[tap]*wre - nI[tap]*wim;
                accI[co] += nR[tap]*wim + nI[tap]*wre;
            }
    }
#pragma unroll
    for (int co = 0; co < 16; ++co) {
        S1r[sidx(b, co, s, u, v)] = accR[co];
        S1i[sidx(b, co, s, u, v)] = accI[co];
    }
}

// stage 2: 16->16 conv strips->strips, u in [u0, u0+3). grid (16, cb).
__global__ __launch_bounds__(256) void strip_mid(
    const float* __restrict__ Ar, const float* __restrict__ Ai,
    const float* __restrict__ wr_, const float* __restrict__ wi_, // [b][16][16][9]
    float* __restrict__ Br, float* __restrict__ Bi) {
    __shared__ float sW[16*16*9*2];
    const int s = blockIdx.x >> 2, vt = blockIdx.x & 3, b = blockIdx.y;
    for (int t = threadIdx.x; t < 2304; t += 256) {
        sW[2*t] = wr_[(size_t)b*2304 + t]; sW[2*t+1] = wi_[(size_t)b*2304 + t];
    }
    __syncthreads();
    const int v = vt * 64 + (threadIdx.x & 63);
    const int uslot = threadIdx.x >> 6;
    if (uslot >= 3) return;
    const int u0 = (s == 1 || s == 3) ? 1 : 0;
    const int u = u0 + uslot;
    int y, x; spos(s, u, v, y, x);
    float accR[16], accI[16];
#pragma unroll
    for (int co = 0; co < 16; ++co) { accR[co] = 0.f; accI[co] = 0.f; }
    for (int ci = 0; ci < 16; ++ci) {
        float nR[9], nI[9];
#pragma unroll
        for (int dy = -1; dy <= 1; ++dy)
#pragma unroll
            for (int dx = -1; dx <= 1; ++dx) {
                int gy = y + dy, gx = x + dx;
                float vr = 0.f, vi = 0.f;
                if (((unsigned)gy < G) & ((unsigned)gx < G)) {
                    int up = (s < 2) ? u + dy : u + dx;
                    int vp = (s < 2) ? v + dx : v + dy;
                    size_t ix = sidx(b, ci, s, up, vp);
                    vr = Ar[ix]; vi = Ai[ix];
                }
                nR[(dy+1)*3+dx+1] = vr; nI[(dy+1)*3+dx+1] = vi;
            }
#pragma unroll
        for (int co = 0; co < 16; ++co)
#pragma unroll
            for (int tap = 0; tap < 9; ++tap) {
                float wre = sW[((co*16+ci)*9+tap)*2];
                float wim = sW[((co*16+ci)*9+tap)*2+1];
                accR[co] += nR[tap]*wre - nI[tap]*wim;
                accI[co] += nR[tap]*wim + nI[tap]*wre;
            }
    }
#pragma unroll
    for (int co = 0; co < 16; ++co) {
        Br[sidx(b, co, s, u, v)] = accR[co];
        Bi[sidx(b, co, s, u, v)] = accI[co];
    }
}

// stage 3: COUT ch from strips -> overwrite band in full planes, u in [u0,u0+2). grid (16, cb).
template<int COUT>
__global__ __launch_bounds__(256) void strip_fin(
    const float* __restrict__ Ar, const float* __restrict__ Ai,
    const float* __restrict__ wr_, const float* __restrict__ wi_, // [b][COUT][16][9]
    float* __restrict__ Or, float* __restrict__ Oi) {
    __shared__ float sW[COUT*16*9*2];
    const int s = blockIdx.x >> 2, vt = blockIdx.x & 3, b = blockIdx.y;
    for (int t = threadIdx.x; t < COUT*144; t += 256) {
        sW[2*t] = wr_[(size_t)b*COUT*144 + t]; sW[2*t+1] = wi_[(size_t)b*COUT*144 + t];
    }
    __syncthreads();
    const int v = vt * 64 + (threadIdx.x & 63);
    const int uslot = threadIdx.x >> 6;
    if (uslot >= 2) return;
    const int u0 = (s == 1 || s == 3) ? 2 : 0;
    const int u = u0 + uslot;
    int y, x; spos(s, u, v, y, x);
    float accR[COUT], accI[COUT];
#pragma unroll
    for (int co = 0; co < COUT; ++co) { accR[co] = 0.f; accI[co] = 0.f; }
    for (int ci = 0; ci < 16; ++ci) {
        float nR[9], nI[9];
#pragma unroll
        for (int dy = -1; dy <= 1; ++dy)
#pragma unroll
            for (int dx = -1; dx <= 1; ++dx) {
                int gy = y + dy, gx = x + dx;
                float vr = 0.f, vi = 0.f;
                if (((unsigned)gy < G) & ((unsigned)gx < G)) {
                    int up = (s < 2) ? u + dy : u + dx;
                    int vp = (s < 2) ? v + dx : v + dy;
                    size_t ix = sidx(b, ci, s, up, vp);
                    vr = Ar[ix]; vi = Ai[ix];
                }
                nR[(dy+1)*3+dx+1] = vr; nI[(dy+1)*3+dx+1] = vi;
            }
#pragma unroll
        for (int co = 0; co < COUT; ++co)
#pragma unroll
            for (int tap = 0; tap < 9; ++tap) {
                float wre = sW[((co*16+ci)*9+tap)*2];
                float wim = sW[((co*16+ci)*9+tap)*2+1];
                accR[co] += nR[tap]*wre - nI[tap]*wim;
                accI[co] += nR[tap]*wim + nI[tap]*wre;
            }
    }
#pragma unroll
    for (int co = 0; co < COUT; ++co) {
        Or[((size_t)b*COUT + co)*GG + y*G + x] = accR[co];
        Oi[((size_t)b*COUT + co)*GG + y*G + x] = accI[co];
    }
}

// ---------------------------------------------------------------------------
__global__ __launch_bounds__(256) void fft_stage1(
    const float* __restrict__ hr, const float* __restrict__ hi,
    const float* __restrict__ sintab,
    float* __restrict__ Ur, float* __restrict__ Ui) {
    __shared__ float ss[256];
    ss[threadIdx.x] = sintab[threadIdx.x];
    __syncthreads();
    int idx = blockIdx.x * 256 + threadIdx.x;
    int j2 = idx & 255;
    int t = idx >> 8;
    int k1 = t % N1; int b = t / N1;
    const float* hrb = hr + (size_t)b * GG;
    const float* hib = hi + (size_t)b * GG;
    float ur = 0.f, ui = 0.f;
    for (int j1 = 0; j1 < G; ++j1) {
        int ph = (k1 * j1) & 255;
        float s = ss[ph], c = ss[(ph + 64) & 255];
        float xr = hrb[j1 * G + j2], xi = hib[j1 * G + j2];
        ur += xr * c + xi * s;
        ui += xi * c - xr * s;
    }
    Ur[idx] = ur; Ui[idx] = ui;
}

__global__ __launch_bounds__(256) void fft_stage2(
    const float* __restrict__ Ur, const float* __restrict__ Ui,
    const float* __restrict__ sintab, float* __restrict__ out, int nb) {
    __shared__ float ss[256];
    ss[threadIdx.x] = sintab[threadIdx.x];
    __syncthreads();
    int idx = blockIdx.x * 256 + threadIdx.x;
    if (idx >= nb * N1 * N1) return;
    int k2 = idx % N1;
    int t = idx / N1;
    int k1 = t % N1; int b = t / N1;
    const float* urb = Ur + ((size_t)b * N1 + k1) * G;
    const float* uib = Ui + ((size_t)b * N1 + k1) * G;
    float acc = 0.f;
    for (int j2 = 0; j2 < G; ++j2) {
        int ph = (k2 * j2) & 255;
        float s = ss[ph], c = ss[(ph + 64) & 255];
        acc += urb[j2] * c + uib[j2] * s;
    }
    out[idx] = ((k1 + k2) & 1) ? -acc : acc;
}

// ---------------------------------------------------------------------------
extern "C" void kernel_launch(void* const* d_in, const int* in_sizes, int n_in,
                              void* d_out, int out_size, void* d_ws, size_t ws_size,
                              hipStream_t stream) {
    const float* r   = (const float*)d_in[0];
    const float* w1r = (const float*)d_in[1];
    const float* w1i = (const float*)d_in[2];
    const float* w2r = (const float*)d_in[3];
    const float* w2i = (const float*)d_in[4];
    const float* w3r = (const float*)d_in[5];
    const float* w3i = (const float*)d_in[6];
    const float* wtr = (const float*)d_in[7];
    const float* wti = (const float*)d_in[8];
    float* out = (float*)d_out;

    float* ws = (float*)d_ws;
    const size_t g = (size_t)GG;

    // ---- fixed region ---------------------------------------------------
    const size_t SZ16 = (size_t)NB*CH*CH*9;   // 73728
    const size_t SZ1  = (size_t)NB*CH*9;      // 4608
    const size_t SZ5  = (size_t)NB*16*25;
    const size_t SZ7  = (size_t)NB*16*49;
    float* p = ws;
    float* SIN  = p; p += 1024;
    float* A3R = p; p += SZ16;  float* A3I = p; p += SZ16;
    float* A2R = p; p += SZ16;  float* A2I = p; p += SZ16;
    float* A1R = p; p += SZ1;   float* A1I = p; p += SZ1;
    float* C5R = p; p += SZ5;   float* C5I = p; p += SZ5;
    float* C7FR = p; p += SZ7;  float* C7FI = p; p += SZ7;
    float* Q5R = p; p += SZ5;   float* Q5I = p; p += SZ5;
    float* C7AR = p; p += SZ7;  float* C7AI = p; p += SZ7;
    const size_t extraFloats = (size_t)(p - ws);

    // ---- adaptive chunking ---------------------------------------------
    // per-sample floats: A(32g) + RHAT(g) + T1(g/2) + S1(2g) + S2(2g) + HC(2g)
    //                  + U(1.5g) + PTA(5g)
    const size_t sampFloats = 32*g + g + g/2 + 2*g + 2*g + 2*g + g + g/2 + 5*g;
    size_t availFloats = ws_size / 4;
    long long usable = (long long)availFloats - (long long)extraFloats;
    int cbm = 1;
    if (usable > 0) {
        long long c = usable / (long long)sampFloats;
        cbm = (int)(c < 1 ? 1 : (c > NB ? NB : c));
    }

    float* base = ws + extraFloats;
    float* A_RE = base;
    float* A_IM = A_RE + (size_t)cbm*16*g;
    float* RHAT = A_IM + (size_t)cbm*16*g;
    float* T1D  = RHAT + (size_t)cbm*g;
    float* S1r  = T1D + (size_t)cbm*(g/2);
    float* S1i  = S1r + (size_t)cbm*g;
    float* S2r  = S1i + (size_t)cbm*g;
    float* S2i  = S2r + (size_t)cbm*g;
    float* HCr  = S2i + (size_t)cbm*g;
    float* HCi  = HCr + (size_t)cbm*g;
    float* Ur   = HCi + (size_t)cbm*g;
    float* Ui   = Ur + (size_t)cbm*(g/2);
    float* PTA  = Ui + (size_t)cbm*(g/2);      // [cb][16][4][5][256][2] = 5g/sample

    // ---- one-time prep --------------------------------------------------
    hipLaunchKernelGGL(init_sintab, dim3(1), dim3(256), 0, stream, SIN);
    hipLaunchKernelGGL(prep_adj16, dim3((unsigned)((SZ16+255)/256)), dim3(256), 0, stream,
                       w3r, w3i, A3R, A3I);
    hipLaunchKernelGGL(prep_adj16, dim3((unsigned)((SZ16+255)/256)), dim3(256), 0, stream,
                       w2r, w2i, A2R, A2I);
    hipLaunchKernelGGL(prep_adj1,  dim3((unsigned)((SZ1+255)/256)),  dim3(256), 0, stream,
                       w1r, w1i, A1R, A1I);
    hipLaunchKernelGGL((compose_k<16,16,1,3,3>), dim3((unsigned)((NB*16*25+255)/256)), dim3(256),
                       0, stream, w2r, w2i, w1r, w1i, C5R, C5I);
    hipLaunchKernelGGL((compose_k<16,16,1,3,5>), dim3((unsigned)((NB*16*49+255)/256)), dim3(256),
                       0, stream, w3r, w3i, C5R, C5I, C7FR, C7FI);
    hipLaunchKernelGGL((compose_k<1,16,16,3,3>), dim3((unsigned)((NB*16*25+255)/256)), dim3(256),
                       0, stream, A1R, A1I, A2R, A2I, Q5R, Q5I);
    hipLaunchKernelGGL((compose_k<1,16,16,5,3>), dim3((unsigned)((NB*16*49+255)/256)), dim3(256),
                       0, stream, Q5R, Q5I, A3R, A3I, C7AR, C7AI);

    // ---- per-chunk pipeline --------------------------------------------
    for (int b0 = 0; b0 < NB; b0 += cbm) {
        const int cb = (NB - b0) < cbm ? (NB - b0) : cbm;

        const float* r_c    = r    + (size_t)b0 * N1 * N1;
        const float* w1r_c  = w1r  + (size_t)b0 * 144;
        const float* w1i_c  = w1i  + (size_t)b0 * 144;
        const float* w2r_c  = w2r  + (size_t)b0 * 2304;
        const float* w2i_c  = w2i  + (size_t)b0 * 2304;
        const float* w3r_c  = w3r  + (size_t)b0 * 2304;
        const float* w3i_c  = w3i  + (size_t)b0 * 2304;
        const float* a3r_c  = A3R  + (size_t)b0 * 2304;
        const float* a3i_c  = A3I  + (size_t)b0 * 2304;
        const float* a2r_c  = A2R  + (size_t)b0 * 2304;
        const float* a2i_c  = A2I  + (size_t)b0 * 2304;
        const float* a1r_c  = A1R  + (size_t)b0 * 144;
        const float* a1i_c  = A1I  + (size_t)b0 * 144;
        const float* c7fr_c = C7FR + (size_t)b0 * 784;
        const float* c7fi_c = C7FI + (size_t)b0 * 784;
        const float* c7ar_c = C7AR + (size_t)b0 * 784;
        const float* c7ai_c = C7AI + (size_t)b0 * 784;
        const float* wtr_c  = wtr  + (size_t)b0 * CH * GG;
        const float* wti_c  = wti  + (size_t)b0 * CH * GG;
        float* out_c = out + (size_t)b0 * N1 * N1;

        hipLaunchKernelGGL(dst_stage1, dim3((cb*G*N1 + 255)/256), dim3(256), 0, stream,
                           r_c, SIN, T1D, cb);
        hipLaunchKernelGGL(dst_stage2, dim3(cb*256), dim3(256), 0, stream,
                           T1D, SIN, RHAT);

        hipLaunchKernelGGL(fwd7_kernel, dim3(128, cb), dim3(256), 0, stream,
                           RHAT, c7fr_c, c7fi_c, A_RE, A_IM);
        hipLaunchKernelGGL(strip_fwd1, dim3(4, cb), dim3(256), 0, stream,
                           RHAT, w1r_c, w1i_c, S1r, S1i);
        hipLaunchKernelGGL(strip_mid, dim3(16, cb), dim3(256), 0, stream,
                           S1r, S1i, w2r_c, w2i_c, S2r, S2i);
        hipLaunchKernelGGL((strip_fin<16>), dim3(16, cb), dim3(256), 0, stream,
                           S2r, S2i, w3r_c, w3i_c, A_RE, A_IM);

        hipLaunchKernelGGL(adj7_kernel, dim3(32, cb), dim3(256), 0, stream,
                           A_RE, A_IM, wtr_c, wti_c, c7ar_c, c7ai_c, HCr, HCi, PTA);
        hipLaunchKernelGGL(strip_adj1_packed, dim3(16, cb), dim3(256), 0, stream,
                           PTA, a3r_c, a3i_c, S1r, S1i);
        hipLaunchKernelGGL(strip_mid, dim3(16, cb), dim3(256), 0, stream,
                           S1r, S1i, a2r_c, a2i_c, S2r, S2i);
        hipLaunchKernelGGL((strip_fin<1>), dim3(16, cb), dim3(256), 0, stream,
                           S2r, S2i, a1r_c, a1i_c, HCr, HCi);

        hipLaunchKernelGGL(fft_stage1, dim3(cb*N1), dim3(256), 0, stream,
                           HCr, HCi, SIN, Ur, Ui);
        hipLaunchKernelGGL(fft_stage2, dim3((cb*N1*N1 + 255)/256), dim3(256), 0, stream,
                           Ur, Ui, SIN, out_c, cb);
    }
}

// Round 6
// 1250.758 us; speedup vs baseline: 1.1836x; 1.1836x over previous
//
#include <hip/hip_runtime.h>
#include <hip/hip_bf16.h>
#include <math.h>

#define NB 32
#define CH 16
#define N1 127
#define G 256
#define GG (G*G)

// ---------------------------------------------------------------------------
__global__ void init_sintab(float* __restrict__ sintab) {
    int t = threadIdx.x;
    sintab[t] = sinf(6.28318530717958647692f * (float)t / 256.0f);
}

// adj(w)[b,a,c,ky,kx] = conj(w[b,c,a,kx,ky])
__global__ __launch_bounds__(256) void prep_adj16(
    const float* __restrict__ wr, const float* __restrict__ wi,
    float* __restrict__ our, float* __restrict__ oui) {
    int idx = blockIdx.x * 256 + threadIdx.x;
    if (idx >= NB*CH*CH*9) return;
    int tap = idx % 9; int t = idx / 9;
    int c = t % CH; t /= CH;
    int a = t % CH; int b = t / CH;
    int ky = tap / 3, kx = tap % 3;
    int src = ((b*CH + c)*CH + a)*9 + kx*3 + ky;
    our[idx] = wr[src];
    oui[idx] = -wi[src];
}

__global__ __launch_bounds__(256) void prep_adj1(
    const float* __restrict__ wr, const float* __restrict__ wi,
    float* __restrict__ our, float* __restrict__ oui) {
    int idx = blockIdx.x * 256 + threadIdx.x;
    if (idx >= NB*CH*9) return;
    int tap = idx % 9; int t = idx / 9;
    int c = t % CH; int b = t / CH;
    int ky = tap / 3, kx = tap % 3;
    int src = (b*CH + c)*9 + kx*3 + ky;
    our[idx] = wr[src];
    oui[idx] = -wi[src];
}

// ---------------------------------------------------------------------------
// Kernel-tap composition: R[t] = sum_{a+b=t} P[a] Q[b]  (complex), contract CM
template<int CO, int CM, int CI, int KP, int KQ>
__global__ __launch_bounds__(256) void compose_k(
    const float* __restrict__ Pr, const float* __restrict__ Pi,
    const float* __restrict__ Qr, const float* __restrict__ Qi,
    float* __restrict__ Rr, float* __restrict__ Ri) {
    constexpr int T = KP + KQ - 1;
    int idx = blockIdx.x * 256 + threadIdx.x;
    if (idx >= NB*CO*CI*T*T) return;
    int txp = idx % T; int t = idx / T;
    int typ = t % T; t /= T;
    int ci = t % CI; t /= CI;
    int co = t % CO; int b = t / CO;
    float ar = 0.f, ai = 0.f;
    for (int m = 0; m < CM; ++m) {
        const float* pr = Pr + (((size_t)b*CO + co)*CM + m)*KP*KP;
        const float* pi = Pi + (((size_t)b*CO + co)*CM + m)*KP*KP;
        const float* qr = Qr + (((size_t)b*CM + m)*CI + ci)*KQ*KQ;
        const float* qi = Qi + (((size_t)b*CM + m)*CI + ci)*KQ*KQ;
        for (int ay = 0; ay < KP; ++ay) {
            int by = typ - ay; if (by < 0 || by >= KQ) continue;
            for (int ax = 0; ax < KP; ++ax) {
                int bx = txp - ax; if (bx < 0 || bx >= KQ) continue;
                float prr = pr[ay*KP+ax], pii = pi[ay*KP+ax];
                float qrr = qr[by*KQ+bx], qii = qi[by*KQ+bx];
                ar += prr*qrr - pii*qii;
                ai += prr*qii + pii*qrr;
            }
        }
    }
    Rr[idx] = ar; Ri[idx] = ai;
}

// ---------------------------------------------------------------------------
// DST stage 1  ((-1)^K folded into sin index: sin(th+piK)=(-1)^K sin th)
__global__ __launch_bounds__(256) void dst_stage1(
    const float* __restrict__ r, const float* __restrict__ sintab,
    float* __restrict__ T1, int nb) {
    __shared__ float ss[256];
    ss[threadIdx.x] = sintab[threadIdx.x];
    __syncthreads();
    int idx = blockIdx.x * 256 + threadIdx.x;
    if (idx >= nb*G*N1) return;
    int kk = idx % N1;
    int t = idx / N1;
    int j1 = t & 255; int b = t >> 8;
    const float* rb = r + b * N1 * N1;
    const int j1s = (j1 + 128) & 255;
    float acc = 0.f;
    for (int K = 1; K <= N1; ++K) {
        acc = fmaf(ss[(j1s * K) & 255], rb[(K - 1) * N1 + kk], acc);
    }
    T1[idx] = acc;
}

// DST stage 2  ((-1)^{kk+1} folded likewise)
__global__ __launch_bounds__(256) void dst_stage2(
    const float* __restrict__ T1, const float* __restrict__ sintab,
    float* __restrict__ rhat) {
    __shared__ float ss[256];
    ss[threadIdx.x] = sintab[threadIdx.x];
    __syncthreads();
    int idx = blockIdx.x * 256 + threadIdx.x;
    int j2 = idx & 255;
    int t = idx >> 8;
    int j1 = t & 255; int b = t >> 8;
    const float* t1 = T1 + ((size_t)b * G + j1) * N1;
    const int j2s = (j2 + 128) & 255;
    float acc = 0.f;
    for (int kk = 0; kk < N1; ++kk) {
        acc = fmaf(ss[(j2s * (kk + 1)) & 255], t1[kk], acc);
    }
    rhat[idx] = acc * (-4.0f / 65536.0f);
}

// ---------------------------------------------------------------------------
// Forward composed 7x7 conv: rhat (real, 1ch) -> A (16ch complex)
__global__ __launch_bounds__(256) void fwd7_kernel(
    const float* __restrict__ rhat,
    const float* __restrict__ w7r, const float* __restrict__ w7i, // [b][16][49]
    float* __restrict__ yr, float* __restrict__ yi) {
    __shared__ float sW[16*49*2];
    __shared__ float sIn[22*38];
    const int b = blockIdx.y;
    const int tile = blockIdx.x;            // 8 x-tiles (32) x 16 y-tiles (16)
    const int x0 = (tile & 7) * 32;
    const int y0 = (tile >> 3) * 16;
    const int tid = threadIdx.x;
    const float* wrb = w7r + (size_t)b * 784;
    const float* wib = w7i + (size_t)b * 784;
    for (int t = tid; t < 784; t += 256) { sW[2*t] = wrb[t]; sW[2*t+1] = wib[t]; }
    const float* rb = rhat + (size_t)b * GG;
    for (int t = tid; t < 22*38; t += 256) {
        int rr = t / 38, cc = t - rr * 38;
        int gy = y0 + rr - 3, gx = x0 + cc - 3;
        bool ok = ((unsigned)gy < G) & ((unsigned)gx < G);
        sIn[t] = ok ? rb[gy * G + gx] : 0.f;
    }
    __syncthreads();
    const int tx = tid & 31;
    const int ty = tid >> 5;    // 0..7
    float accR[2][16], accI[2][16];
#pragma unroll
    for (int p = 0; p < 2; ++p)
#pragma unroll
        for (int co = 0; co < 16; ++co) { accR[p][co] = 0.f; accI[p][co] = 0.f; }
#pragma unroll
    for (int tap = 0; tap < 49; ++tap) {
        const int dy = tap / 7, dx = tap % 7;
        float x0v = sIn[(ty + dy) * 38 + tx + dx];
        float x1v = sIn[(ty + 8 + dy) * 38 + tx + dx];
#pragma unroll
        for (int co = 0; co < 16; ++co) {
            const float2 wv = *reinterpret_cast<const float2*>(&sW[(co*49 + tap)*2]);
            accR[0][co] = fmaf(x0v, wv.x, accR[0][co]);
            accI[0][co] = fmaf(x0v, wv.y, accI[0][co]);
            accR[1][co] = fmaf(x1v, wv.x, accR[1][co]);
            accI[1][co] = fmaf(x1v, wv.y, accI[1][co]);
        }
    }
    const size_t outB = (size_t)b * 16 * GG;
#pragma unroll
    for (int co = 0; co < 16; ++co)
#pragma unroll
        for (int p = 0; p < 2; ++p) {
            int oy = y0 + ty + p * 8, ox = x0 + tx;
            yr[outB + (size_t)co * GG + oy * G + ox] = accR[p][co];
            yi[outB + (size_t)co * GG + oy * G + ox] = accI[p][co];
        }
}

// ---------------------------------------------------------------------------
// Adjoint composed 7x7 conv with fused theta: (A .* theta) (16ch) -> HC (1ch).
// Round-4 conflict-free mapping (4x2 outputs per thread, per-tap b64 reads)
// + LDS double-buffer with T14 async staging: issue ci+1 loads, compute ci,
// then multiply+ds_write+PTA extraction, one barrier per ci.
__global__ __launch_bounds__(256) void adj7_kernel(
    const float* __restrict__ xr, const float* __restrict__ xi,
    const float* __restrict__ tr, const float* __restrict__ ti,
    const float* __restrict__ w7r, const float* __restrict__ w7i, // [b][16][49]
    float* __restrict__ or_, float* __restrict__ oi_,
    float* __restrict__ PTA) {
    constexpr int NPX = 38*70;          // 2660 staged pixels
    constexpr int NIT = 11;             // ceil(2660/256)
    __shared__ float sW[16*49*2];
    __shared__ float sIn[2][NPX*2];
    const int b = blockIdx.y;
    const int tile = blockIdx.x;        // 4 x-tiles (64) x 8 y-tiles (32)
    const int x0 = (tile & 3) * 64;
    const int y0 = (tile >> 2) * 32;
    const int tid = threadIdx.x;
    const float* wrb = w7r + (size_t)b * 784;
    const float* wib = w7i + (size_t)b * 784;
    for (int t = tid; t < 784; t += 256) { sW[2*t] = wrb[t]; sW[2*t+1] = wib[t]; }

    // precompute ci-invariant staging positions: packed gy*256+gx, -1 if OOB
    int ppos[NIT];
#pragma unroll
    for (int i = 0; i < NIT; ++i) {
        int t = tid + i*256;
        int rr = t / 70, cc = t - rr*70;
        int gy = y0 + rr - 3, gx = x0 + cc - 3;
        bool ok = (t < NPX) & ((unsigned)gy < G) & ((unsigned)gx < G);
        ppos[i] = ok ? (gy * G + gx) : -1;
    }

    const int tx = tid & 31;
    const int ty = tid >> 5;            // 0..7
    float accR[8], accI[8];
#pragma unroll
    for (int k = 0; k < 8; ++k) { accR[k] = 0.f; accI[k] = 0.f; }

    const size_t planeB = (size_t)b * 16 * GG;
    const size_t cbase0 = ((size_t)b * 16) * 4;

    // ---- prologue: stage ci=0 into buffer 0 (with PTA extraction) -------
    {
        const float* xrc = xr + planeB;
        const float* xic = xi + planeB;
        const float* trc = tr + planeB;
        const float* tic = ti + planeB;
#pragma unroll
        for (int i = 0; i < NIT; ++i) {
            int t = tid + i*256;
            if (t >= NPX) continue;
            float hr = 0.f, hi = 0.f;
            int pp = ppos[i];
            if (pp >= 0) {
                float ar = xrc[pp], ai = xic[pp];
                float cr = trc[pp], cv = tic[pp];
                hr = fmaf(ar, cr, -ai*cv);
                hi = fmaf(ar, cv,  ai*cr);
                int gy = pp >> 8, gx = pp & 255;
                if (gy < 5)    { size_t o = ((cbase0 + 0)*5 + gy      )*256 + gx; PTA[2*o] = hr; PTA[2*o+1] = hi; }
                if (gy >= 251) { size_t o = ((cbase0 + 1)*5 + gy - 251)*256 + gx; PTA[2*o] = hr; PTA[2*o+1] = hi; }
                if (gx < 5)    { size_t o = ((cbase0 + 2)*5 + gx      )*256 + gy; PTA[2*o] = hr; PTA[2*o+1] = hi; }
                if (gx >= 251) { size_t o = ((cbase0 + 3)*5 + gx - 251)*256 + gy; PTA[2*o] = hr; PTA[2*o+1] = hi; }
            }
            sIn[0][2*t] = hr; sIn[0][2*t+1] = hi;
        }
    }
    __syncthreads();

    int cur = 0;
    for (int ci = 0; ci < 16; ++ci) {
        // ---- issue prefetch loads for ci+1 (latency hidden by FMA block) --
        float par[NIT], pai[NIT], pcr[NIT], pcv[NIT];
        const bool havenext = (ci < 15);
        if (havenext) {
            const float* xrc = xr + planeB + (size_t)(ci+1) * GG;
            const float* xic = xi + planeB + (size_t)(ci+1) * GG;
            const float* trc = tr + planeB + (size_t)(ci+1) * GG;
            const float* tic = ti + planeB + (size_t)(ci+1) * GG;
#pragma unroll
            for (int i = 0; i < NIT; ++i) {
                int pp = ppos[i];
                if (pp >= 0) {
                    par[i] = xrc[pp]; pai[i] = xic[pp];
                    pcr[i] = trc[pp]; pcv[i] = tic[pp];
                } else { par[i] = 0.f; pai[i] = 0.f; pcr[i] = 0.f; pcv[i] = 0.f; }
            }
        }

        // ---- compute ci from sIn[cur] ------------------------------------
        const float* wci = &sW[ci*49*2];
        const float* bufc = &sIn[cur][0];
#pragma unroll 7
        for (int tap = 0; tap < 49; ++tap) {
            const int dy = tap / 7, dx = tap % 7;
            const float2 wv = *reinterpret_cast<const float2*>(&wci[tap*2]);
#pragma unroll
            for (int ry = 0; ry < 4; ++ry)
#pragma unroll
                for (int cx = 0; cx < 2; ++cx) {
                    int k = ry*2 + cx;
                    const float2 xv = *reinterpret_cast<const float2*>(
                        &bufc[((ty + 8*ry + dy) * 70 + tx + 32*cx + dx) * 2]);
                    accR[k] = fmaf(xv.x, wv.x, accR[k]);
                    accR[k] = fmaf(-xv.y, wv.y, accR[k]);
                    accI[k] = fmaf(xv.x, wv.y, accI[k]);
                    accI[k] = fmaf(xv.y, wv.x, accI[k]);
                }
        }

        // ---- theta-multiply + write next buffer + PTA --------------------
        if (havenext) {
            float* bufn = &sIn[cur ^ 1][0];
            const size_t cbase = ((size_t)b*16 + (ci+1)) * 4;
#pragma unroll
            for (int i = 0; i < NIT; ++i) {
                int t = tid + i*256;
                if (t >= NPX) continue;
                float hr = 0.f, hi = 0.f;
                int pp = ppos[i];
                if (pp >= 0) {
                    hr = fmaf(par[i], pcr[i], -pai[i]*pcv[i]);
                    hi = fmaf(par[i], pcv[i],  pai[i]*pcr[i]);
                    int gy = pp >> 8, gx = pp & 255;
                    if (gy < 5)    { size_t o = ((cbase + 0)*5 + gy      )*256 + gx; PTA[2*o] = hr; PTA[2*o+1] = hi; }
                    if (gy >= 251) { size_t o = ((cbase + 1)*5 + gy - 251)*256 + gx; PTA[2*o] = hr; PTA[2*o+1] = hi; }
                    if (gx < 5)    { size_t o = ((cbase + 2)*5 + gx      )*256 + gy; PTA[2*o] = hr; PTA[2*o+1] = hi; }
                    if (gx >= 251) { size_t o = ((cbase + 3)*5 + gx - 251)*256 + gy; PTA[2*o] = hr; PTA[2*o+1] = hi; }
                }
                bufn[2*t] = hr; bufn[2*t+1] = hi;
            }
        }
        __syncthreads();
        cur ^= 1;
    }

    const size_t outB = (size_t)b * GG;
#pragma unroll
    for (int ry = 0; ry < 4; ++ry)
#pragma unroll
        for (int cx = 0; cx < 2; ++cx) {
            int oy = y0 + ty + 8*ry, ox = x0 + tx + 32*cx;
            or_[outB + oy*G + ox] = accR[ry*2+cx];
            oi_[outB + oy*G + ox] = accI[ry*2+cx];
        }
}

// ---------------------------------------------------------------------------
// Strip machinery. strip s: 0=TOP(rows 0..3), 1=BOT(rows 252..255),
// 2=LEF(cols 0..3), 3=RIG(cols 252..255). Packed [b][ch][s][u:4][v:256].
__device__ __forceinline__ size_t sidx(int b, int ch, int s, int u, int v) {
    return ((((size_t)b*CH + ch)*4 + s)*4 + u)*256 + v;
}
__device__ __forceinline__ void spos(int s, int u, int v, int& y, int& x) {
    y = (s == 0) ? u : (s == 1) ? 252 + u : v;
    x = (s == 2) ? u : (s == 3) ? 252 + u : v;
}

// stage 1 fwd: conv1 (w1, 1->16, real rhat) exact, all u in [0,4)
__global__ __launch_bounds__(256) void strip_fwd1(
    const float* __restrict__ rhat,
    const float* __restrict__ w1r_, const float* __restrict__ w1i_, // [b][16][9]
    float* __restrict__ S1r, float* __restrict__ S1i) {
    __shared__ float sW[16*9*2];
    const int s = blockIdx.x, b = blockIdx.y;
    for (int t = threadIdx.x; t < 144; t += 256) {
        sW[2*t] = w1r_[(size_t)b*144 + t]; sW[2*t+1] = w1i_[(size_t)b*144 + t];
    }
    __syncthreads();
    const int v = threadIdx.x;
    const float* rb = rhat + (size_t)b * GG;
    for (int u = 0; u < 4; ++u) {
        int y, x; spos(s, u, v, y, x);
        float xv[9];
#pragma unroll
        for (int dy = -1; dy <= 1; ++dy)
#pragma unroll
            for (int dx = -1; dx <= 1; ++dx) {
                int gy = y + dy, gx = x + dx;
                bool ok = ((unsigned)gy < G) & ((unsigned)gx < G);
                xv[(dy+1)*3 + dx+1] = ok ? rb[gy*G+gx] : 0.f;
            }
#pragma unroll
        for (int co = 0; co < 16; ++co) {
            float ar = 0.f, ai = 0.f;
#pragma unroll
            for (int tap = 0; tap < 9; ++tap) {
                ar = fmaf(xv[tap], sW[(co*9+tap)*2], ar);
                ai = fmaf(xv[tap], sW[(co*9+tap)*2+1], ai);
            }
            S1r[sidx(b, co, s, u, v)] = ar;
            S1i[sidx(b, co, s, u, v)] = ai;
        }
    }
}

// stage 1 adj (packed): a3-conv on packed theta.*A bands. u in [0,4).
// grid (16, cb): blockIdx.x = s*4 + vtile; threads 256 = 64v x 4u.
__global__ __launch_bounds__(256) void strip_adj1_packed(
    const float* __restrict__ PTA,   // [b][ci][4][5][256][2]
    const float* __restrict__ wr_, const float* __restrict__ wi_, // [b][16][16][9]
    float* __restrict__ S1r, float* __restrict__ S1i) {
    __shared__ float sW[16*16*9*2];
    const int s = blockIdx.x >> 2, vt = blockIdx.x & 3, b = blockIdx.y;
    for (int t = threadIdx.x; t < 2304; t += 256) {
        sW[2*t] = wr_[(size_t)b*2304 + t]; sW[2*t+1] = wi_[(size_t)b*2304 + t];
    }
    __syncthreads();
    const int v = vt * 64 + (threadIdx.x & 63);
    const int u = threadIdx.x >> 6;           // 0..3
    const int off = (s == 1 || s == 3) ? 1 : 0;
    float accR[16], accI[16];
#pragma unroll
    for (int co = 0; co < 16; ++co) { accR[co] = 0.f; accI[co] = 0.f; }
    for (int ci = 0; ci < 16; ++ci) {
        const float* base = PTA + ((((size_t)b*16 + ci)*4 + s)*5) * 512;
        float nR[9], nI[9];
#pragma unroll
        for (int dy = -1; dy <= 1; ++dy)
#pragma unroll
            for (int dx = -1; dx <= 1; ++dx) {
                int pu = (s < 2) ? (u + off + dy) : (u + off + dx);
                int vp = (s < 2) ? (v + dx) : (v + dy);
                float vr = 0.f, vi = 0.f;
                if (((unsigned)pu < 5u) & ((unsigned)vp < 256u)) {
                    const float2 pv = *reinterpret_cast<const float2*>(&base[(pu*256 + vp)*2]);
                    vr = pv.x; vi = pv.y;
                }
                nR[(dy+1)*3+dx+1] = vr; nI[(dy+1)*3+dx+1] = vi;
            }
#pragma unroll
        for (int co = 0; co < 16; ++co)
#pragma unroll
            for (int tap = 0; tap < 9; ++tap) {
                float wre = sW[((co*16+ci)*9+tap)*2];
                float wim = sW[((co*16+ci)*9+tap)*2+1];
                accR[co] += nR[tap]*wre - nI[tap]*wim;
                accI[co] += nR[tap]*wim + nI[tap]*wre;
            }
    }
#pragma unroll
    for (int co = 0; co < 16; ++co) {
        S1r[sidx(b, co, s, u, v)] = accR[co];
        S1i[sidx(b, co, s, u, v)] = accI[co];
    }
}

// stage 2: 16->16 conv strips->strips, u in [u0, u0+3). grid (16, cb).
__global__ __launch_bounds__(256) void strip_mid(
    const float* __restrict__ Ar, const float* __restrict__ Ai,
    const float* __restrict__ wr_, const float* __restrict__ wi_, // [b][16][16][9]
    float* __restrict__ Br, float* __restrict__ Bi) {
    __shared__ float sW[16*16*9*2];
    const int s = blockIdx.x >> 2, vt = blockIdx.x & 3, b = blockIdx.y;
    for (int t = threadIdx.x; t < 2304; t += 256) {
        sW[2*t] = wr_[(size_t)b*2304 + t]; sW[2*t+1] = wi_[(size_t)b*2304 + t];
    }
    __syncthreads();
    const int v = vt * 64 + (threadIdx.x & 63);
    const int uslot = threadIdx.x >> 6;
    if (uslot >= 3) return;
    const int u0 = (s == 1 || s == 3) ? 1 : 0;
    const int u = u0 + uslot;
    int y, x; spos(s, u, v, y, x);
    float accR[16], accI[16];
#pragma unroll
    for (int co = 0; co < 16; ++co) { accR[co] = 0.f; accI[co] = 0.f; }
    for (int ci = 0; ci < 16; ++ci) {
        float nR[9], nI[9];
#pragma unroll
        for (int dy = -1; dy <= 1; ++dy)
#pragma unroll
            for (int dx = -1; dx <= 1; ++dx) {
                int gy = y + dy, gx = x + dx;
                float vr = 0.f, vi = 0.f;
                if (((unsigned)gy < G) & ((unsigned)gx < G)) {
                    int up = (s < 2) ? u + dy : u + dx;
                    int vp = (s < 2) ? v + dx : v + dy;
                    size_t ix = sidx(b, ci, s, up, vp);
                    vr = Ar[ix]; vi = Ai[ix];
                }
                nR[(dy+1)*3+dx+1] = vr; nI[(dy+1)*3+dx+1] = vi;
            }
#pragma unroll
        for (int co = 0; co < 16; ++co)
#pragma unroll
            for (int tap = 0; tap < 9; ++tap) {
                float wre = sW[((co*16+ci)*9+tap)*2];
                float wim = sW[((co*16+ci)*9+tap)*2+1];
                accR[co] += nR[tap]*wre - nI[tap]*wim;
                accI[co] += nR[tap]*wim + nI[tap]*wre;
            }
    }
#pragma unroll
    for (int co = 0; co < 16; ++co) {
        Br[sidx(b, co, s, u, v)] = accR[co];
        Bi[sidx(b, co, s, u, v)] = accI[co];
    }
}

// stage 3: COUT ch from strips -> overwrite band in full planes, u in [u0,u0+2). grid (16, cb).
template<int COUT>
__global__ __launch_bounds__(256) void strip_fin(
    const float* __restrict__ Ar, const float* __restrict__ Ai,
    const float* __restrict__ wr_, const float* __restrict__ wi_, // [b][COUT][16][9]
    float* __restrict__ Or, float* __restrict__ Oi) {
    __shared__ float sW[COUT*16*9*2];
    const int s = blockIdx.x >> 2, vt = blockIdx.x & 3, b = blockIdx.y;
    for (int t = threadIdx.x; t < COUT*144; t += 256) {
        sW[2*t] = wr_[(size_t)b*COUT*144 + t]; sW[2*t+1] = wi_[(size_t)b*COUT*144 + t];
    }
    __syncthreads();
    const int v = vt * 64 + (threadIdx.x & 63);
    const int uslot = threadIdx.x >> 6;
    if (uslot >= 2) return;
    const int u0 = (s == 1 || s == 3) ? 2 : 0;
    const int u = u0 + uslot;
    int y, x; spos(s, u, v, y, x);
    float accR[COUT], accI[COUT];
#pragma unroll
    for (int co = 0; co < COUT; ++co) { accR[co] = 0.f; accI[co] = 0.f; }
    for (int ci = 0; ci < 16; ++ci) {
        float nR[9], nI[9];
#pragma unroll
        for (int dy = -1; dy <= 1; ++dy)
#pragma unroll
            for (int dx = -1; dx <= 1; ++dx) {
                int gy = y + dy, gx = x + dx;
                float vr = 0.f, vi = 0.f;
                if (((unsigned)gy < G) & ((unsigned)gx < G)) {
                    int up = (s < 2) ? u + dy : u + dx;
                    int vp = (s < 2) ? v + dx : v + dy;
                    size_t ix = sidx(b, ci, s, up, vp);
                    vr = Ar[ix]; vi = Ai[ix];
                }
                nR[(dy+1)*3+dx+1] = vr; nI[(dy+1)*3+dx+1] = vi;
            }
#pragma unroll
        for (int co = 0; co < COUT; ++co)
#pragma unroll
            for (int tap = 0; tap < 9; ++tap) {
                float wre = sW[((co*16+ci)*9+tap)*2];
                float wim = sW[((co*16+ci)*9+tap)*2+1];
                accR[co] += nR[tap]*wre - nI[tap]*wim;
                accI[co] += nR[tap]*wim + nI[tap]*wre;
            }
    }
#pragma unroll
    for (int co = 0; co < COUT; ++co) {
        Or[((size_t)b*COUT + co)*GG + y*G + x] = accR[co];
        Oi[((size_t)b*COUT + co)*GG + y*G + x] = accI[co];
    }
}

// ---------------------------------------------------------------------------
__global__ __launch_bounds__(256) void fft_stage1(
    const float* __restrict__ hr, const float* __restrict__ hi,
    const float* __restrict__ sintab,
    float* __restrict__ Ur, float* __restrict__ Ui) {
    __shared__ float ss[256];
    ss[threadIdx.x] = sintab[threadIdx.x];
    __syncthreads();
    int idx = blockIdx.x * 256 + threadIdx.x;
    int j2 = idx & 255;
    int t = idx >> 8;
    int k1 = t % N1; int b = t / N1;
    const float* hrb = hr + (size_t)b * GG;
    const float* hib = hi + (size_t)b * GG;
    float ur = 0.f, ui = 0.f;
    for (int j1 = 0; j1 < G; ++j1) {
        int ph = (k1 * j1) & 255;
        float s = ss[ph], c = ss[(ph + 64) & 255];
        float xr = hrb[j1 * G + j2], xi = hib[j1 * G + j2];
        ur += xr * c + xi * s;
        ui += xi * c - xr * s;
    }
    Ur[idx] = ur; Ui[idx] = ui;
}

__global__ __launch_bounds__(256) void fft_stage2(
    const float* __restrict__ Ur, const float* __restrict__ Ui,
    const float* __restrict__ sintab, float* __restrict__ out, int nb) {
    __shared__ float ss[256];
    ss[threadIdx.x] = sintab[threadIdx.x];
    __syncthreads();
    int idx = blockIdx.x * 256 + threadIdx.x;
    if (idx >= nb * N1 * N1) return;
    int k2 = idx % N1;
    int t = idx / N1;
    int k1 = t % N1; int b = t / N1;
    const float* urb = Ur + ((size_t)b * N1 + k1) * G;
    const float* uib = Ui + ((size_t)b * N1 + k1) * G;
    float acc = 0.f;
    for (int j2 = 0; j2 < G; ++j2) {
        int ph = (k2 * j2) & 255;
        float s = ss[ph], c = ss[(ph + 64) & 255];
        acc += urb[j2] * c + uib[j2] * s;
    }
    out[idx] = ((k1 + k2) & 1) ? -acc : acc;
}

// ---------------------------------------------------------------------------
extern "C" void kernel_launch(void* const* d_in, const int* in_sizes, int n_in,
                              void* d_out, int out_size, void* d_ws, size_t ws_size,
                              hipStream_t stream) {
    const float* r   = (const float*)d_in[0];
    const float* w1r = (const float*)d_in[1];
    const float* w1i = (const float*)d_in[2];
    const float* w2r = (const float*)d_in[3];
    const float* w2i = (const float*)d_in[4];
    const float* w3r = (const float*)d_in[5];
    const float* w3i = (const float*)d_in[6];
    const float* wtr = (const float*)d_in[7];
    const float* wti = (const float*)d_in[8];
    float* out = (float*)d_out;

    float* ws = (float*)d_ws;
    const size_t g = (size_t)GG;

    // ---- fixed region ---------------------------------------------------
    const size_t SZ16 = (size_t)NB*CH*CH*9;   // 73728
    const size_t SZ1  = (size_t)NB*CH*9;      // 4608
    const size_t SZ5  = (size_t)NB*16*25;
    const size_t SZ7  = (size_t)NB*16*49;
    float* p = ws;
    float* SIN  = p; p += 1024;
    float* A3R = p; p += SZ16;  float* A3I = p; p += SZ16;
    float* A2R = p; p += SZ16;  float* A2I = p; p += SZ16;
    float* A1R = p; p += SZ1;   float* A1I = p; p += SZ1;
    float* C5R = p; p += SZ5;   float* C5I = p; p += SZ5;
    float* C7FR = p; p += SZ7;  float* C7FI = p; p += SZ7;
    float* Q5R = p; p += SZ5;   float* Q5I = p; p += SZ5;
    float* C7AR = p; p += SZ7;  float* C7AI = p; p += SZ7;
    const size_t extraFloats = (size_t)(p - ws);

    // ---- adaptive chunking ---------------------------------------------
    const size_t sampFloats = 32*g + g + g/2 + 2*g + 2*g + 2*g + g + g/2 + 5*g;
    size_t availFloats = ws_size / 4;
    long long usable = (long long)availFloats - (long long)extraFloats;
    int cbm = 1;
    if (usable > 0) {
        long long c = usable / (long long)sampFloats;
        cbm = (int)(c < 1 ? 1 : (c > NB ? NB : c));
    }

    float* base = ws + extraFloats;
    float* A_RE = base;
    float* A_IM = A_RE + (size_t)cbm*16*g;
    float* RHAT = A_IM + (size_t)cbm*16*g;
    float* T1D  = RHAT + (size_t)cbm*g;
    float* S1r  = T1D + (size_t)cbm*(g/2);
    float* S1i  = S1r + (size_t)cbm*g;
    float* S2r  = S1i + (size_t)cbm*g;
    float* S2i  = S2r + (size_t)cbm*g;
    float* HCr  = S2i + (size_t)cbm*g;
    float* HCi  = HCr + (size_t)cbm*g;
    float* Ur   = HCi + (size_t)cbm*g;
    float* Ui   = Ur + (size_t)cbm*(g/2);
    float* PTA  = Ui + (size_t)cbm*(g/2);      // [cb][16][4][5][256][2] = 5g/sample

    // ---- one-time prep --------------------------------------------------
    hipLaunchKernelGGL(init_sintab, dim3(1), dim3(256), 0, stream, SIN);
    hipLaunchKernelGGL(prep_adj16, dim3((unsigned)((SZ16+255)/256)), dim3(256), 0, stream,
                       w3r, w3i, A3R, A3I);
    hipLaunchKernelGGL(prep_adj16, dim3((unsigned)((SZ16+255)/256)), dim3(256), 0, stream,
                       w2r, w2i, A2R, A2I);
    hipLaunchKernelGGL(prep_adj1,  dim3((unsigned)((SZ1+255)/256)),  dim3(256), 0, stream,
                       w1r, w1i, A1R, A1I);
    hipLaunchKernelGGL((compose_k<16,16,1,3,3>), dim3((unsigned)((NB*16*25+255)/256)), dim3(256),
                       0, stream, w2r, w2i, w1r, w1i, C5R, C5I);
    hipLaunchKernelGGL((compose_k<16,16,1,3,5>), dim3((unsigned)((NB*16*49+255)/256)), dim3(256),
                       0, stream, w3r, w3i, C5R, C5I, C7FR, C7FI);
    hipLaunchKernelGGL((compose_k<1,16,16,3,3>), dim3((unsigned)((NB*16*25+255)/256)), dim3(256),
                       0, stream, A1R, A1I, A2R, A2I, Q5R, Q5I);
    hipLaunchKernelGGL((compose_k<1,16,16,5,3>), dim3((unsigned)((NB*16*49+255)/256)), dim3(256),
                       0, stream, Q5R, Q5I, A3R, A3I, C7AR, C7AI);

    // ---- per-chunk pipeline --------------------------------------------
    for (int b0 = 0; b0 < NB; b0 += cbm) {
        const int cb = (NB - b0) < cbm ? (NB - b0) : cbm;

        const float* r_c    = r    + (size_t)b0 * N1 * N1;
        const float* w1r_c  = w1r  + (size_t)b0 * 144;
        const float* w1i_c  = w1i  + (size_t)b0 * 144;
        const float* w2r_c  = w2r  + (size_t)b0 * 2304;
        const float* w2i_c  = w2i  + (size_t)b0 * 2304;
        const float* w3r_c  = w3r  + (size_t)b0 * 2304;
        const float* w3i_c  = w3i  + (size_t)b0 * 2304;
        const float* a3r_c  = A3R  + (size_t)b0 * 2304;
        const float* a3i_c  = A3I  + (size_t)b0 * 2304;
        const float* a2r_c  = A2R  + (size_t)b0 * 2304;
        const float* a2i_c  = A2I  + (size_t)b0 * 2304;
        const float* a1r_c  = A1R  + (size_t)b0 * 144;
        const float* a1i_c  = A1I  + (size_t)b0 * 144;
        const float* c7fr_c = C7FR + (size_t)b0 * 784;
        const float* c7fi_c = C7FI + (size_t)b0 * 784;
        const float* c7ar_c = C7AR + (size_t)b0 * 784;
        const float* c7ai_c = C7AI + (size_t)b0 * 784;
        const float* wtr_c  = wtr  + (size_t)b0 * CH * GG;
        const float* wti_c  = wti  + (size_t)b0 * CH * GG;
        float* out_c = out + (size_t)b0 * N1 * N1;

        hipLaunchKernelGGL(dst_stage1, dim3((cb*G*N1 + 255)/256), dim3(256), 0, stream,
                           r_c, SIN, T1D, cb);
        hipLaunchKernelGGL(dst_stage2, dim3(cb*256), dim3(256), 0, stream,
                           T1D, SIN, RHAT);

        hipLaunchKernelGGL(fwd7_kernel, dim3(128, cb), dim3(256), 0, stream,
                           RHAT, c7fr_c, c7fi_c, A_RE, A_IM);
        hipLaunchKernelGGL(strip_fwd1, dim3(4, cb), dim3(256), 0, stream,
                           RHAT, w1r_c, w1i_c, S1r, S1i);
        hipLaunchKernelGGL(strip_mid, dim3(16, cb), dim3(256), 0, stream,
                           S1r, S1i, w2r_c, w2i_c, S2r, S2i);
        hipLaunchKernelGGL((strip_fin<16>), dim3(16, cb), dim3(256), 0, stream,
                           S2r, S2i, w3r_c, w3i_c, A_RE, A_IM);

        hipLaunchKernelGGL(adj7_kernel, dim3(32, cb), dim3(256), 0, stream,
                           A_RE, A_IM, wtr_c, wti_c, c7ar_c, c7ai_c, HCr, HCi, PTA);
        hipLaunchKernelGGL(strip_adj1_packed, dim3(16, cb), dim3(256), 0, stream,
                           PTA, a3r_c, a3i_c, S1r, S1i);
        hipLaunchKernelGGL(strip_mid, dim3(16, cb), dim3(256), 0, stream,
                           S1r, S1i, a2r_c, a2i_c, S2r, S2i);
        hipLaunchKernelGGL((strip_fin<1>), dim3(16, cb), dim3(256), 0, stream,
                           S2r, S2i, a1r_c, a1i_c, HCr, HCi);

        hipLaunchKernelGGL(fft_stage1, dim3(cb*N1), dim3(256), 0, stream,
                           HCr, HCi, SIN, Ur, Ui);
        hipLaunchKernelGGL(fft_stage2, dim3((cb*N1*N1 + 255)/256), dim3(256), 0, stream,
                           Ur, Ui, SIN, out_c, cb);
    }
}

// Round 7
// 1042.106 us; speedup vs baseline: 1.4206x; 1.2002x over previous
//
#include <hip/hip_runtime.h>
#include <hip/hip_bf16.h>
#include <math.h>

#define NB 32
#define CH 16
#define N1 127
#define G 256
#define GG (G*G)

typedef float v2f __attribute__((ext_vector_type(2)));

// acc(lo=Re,hi=Im) += complex(x) * complex(w);  x=(xr,xi), w=(wr,wi)
#define CFMA(acc, x, w) do { \
  asm("v_pk_fma_f32 %0, %1, %2, %0 op_sel:[0,0,0] op_sel_hi:[0,1,1]" \
      : "+v"(acc) : "v"(x), "v"(w)); \
  asm("v_pk_fma_f32 %0, %1, %2, %0 op_sel:[1,1,0] op_sel_hi:[1,0,1] neg_lo:[0,1,0]" \
      : "+v"(acc) : "v"(x), "v"(w)); \
} while (0)
// acc += real(x.lo) * complex(w)
#define RFMA_LO(acc, x, w) \
  asm("v_pk_fma_f32 %0, %1, %2, %0 op_sel:[0,0,0] op_sel_hi:[0,1,1]" \
      : "+v"(acc) : "v"(x), "v"(w))
// acc += real(x.hi) * complex(w)
#define RFMA_HI(acc, x, w) \
  asm("v_pk_fma_f32 %0, %1, %2, %0 op_sel:[1,0,0] op_sel_hi:[1,1,1]" \
      : "+v"(acc) : "v"(x), "v"(w))

// ---------------------------------------------------------------------------
__global__ void init_sintab(float* __restrict__ sintab) {
    int t = threadIdx.x;
    sintab[t] = sinf(6.28318530717958647692f * (float)t / 256.0f);
}

// adj(w)[b,a,c,ky,kx] = conj(w[b,c,a,kx,ky])
__global__ __launch_bounds__(256) void prep_adj16(
    const float* __restrict__ wr, const float* __restrict__ wi,
    float* __restrict__ our, float* __restrict__ oui) {
    int idx = blockIdx.x * 256 + threadIdx.x;
    if (idx >= NB*CH*CH*9) return;
    int tap = idx % 9; int t = idx / 9;
    int c = t % CH; t /= CH;
    int a = t % CH; int b = t / CH;
    int ky = tap / 3, kx = tap % 3;
    int src = ((b*CH + c)*CH + a)*9 + kx*3 + ky;
    our[idx] = wr[src];
    oui[idx] = -wi[src];
}

__global__ __launch_bounds__(256) void prep_adj1(
    const float* __restrict__ wr, const float* __restrict__ wi,
    float* __restrict__ our, float* __restrict__ oui) {
    int idx = blockIdx.x * 256 + threadIdx.x;
    if (idx >= NB*CH*9) return;
    int tap = idx % 9; int t = idx / 9;
    int c = t % CH; int b = t / CH;
    int ky = tap / 3, kx = tap % 3;
    int src = (b*CH + c)*9 + kx*3 + ky;
    our[idx] = wr[src];
    oui[idx] = -wi[src];
}

// ---------------------------------------------------------------------------
// Kernel-tap composition: R[t] = sum_{a+b=t} P[a] Q[b]  (complex), contract CM
template<int CO, int CM, int CI, int KP, int KQ>
__global__ __launch_bounds__(256) void compose_k(
    const float* __restrict__ Pr, const float* __restrict__ Pi,
    const float* __restrict__ Qr, const float* __restrict__ Qi,
    float* __restrict__ Rr, float* __restrict__ Ri) {
    constexpr int T = KP + KQ - 1;
    int idx = blockIdx.x * 256 + threadIdx.x;
    if (idx >= NB*CO*CI*T*T) return;
    int txp = idx % T; int t = idx / T;
    int typ = t % T; t /= T;
    int ci = t % CI; t /= CI;
    int co = t % CO; int b = t / CO;
    float ar = 0.f, ai = 0.f;
    for (int m = 0; m < CM; ++m) {
        const float* pr = Pr + (((size_t)b*CO + co)*CM + m)*KP*KP;
        const float* pi = Pi + (((size_t)b*CO + co)*CM + m)*KP*KP;
        const float* qr = Qr + (((size_t)b*CM + m)*CI + ci)*KQ*KQ;
        const float* qi = Qi + (((size_t)b*CM + m)*CI + ci)*KQ*KQ;
        for (int ay = 0; ay < KP; ++ay) {
            int by = typ - ay; if (by < 0 || by >= KQ) continue;
            for (int ax = 0; ax < KP; ++ax) {
                int bx = txp - ax; if (bx < 0 || bx >= KQ) continue;
                float prr = pr[ay*KP+ax], pii = pi[ay*KP+ax];
                float qrr = qr[by*KQ+bx], qii = qi[by*KQ+bx];
                ar += prr*qrr - pii*qii;
                ai += prr*qii + pii*qrr;
            }
        }
    }
    Rr[idx] = ar; Ri[idx] = ai;
}

// ---------------------------------------------------------------------------
// DST stage 1  ((-1)^K folded into sin index)
__global__ __launch_bounds__(256) void dst_stage1(
    const float* __restrict__ r, const float* __restrict__ sintab,
    float* __restrict__ T1, int nb) {
    __shared__ float ss[256];
    ss[threadIdx.x] = sintab[threadIdx.x];
    __syncthreads();
    int idx = blockIdx.x * 256 + threadIdx.x;
    if (idx >= nb*G*N1) return;
    int kk = idx % N1;
    int t = idx / N1;
    int j1 = t & 255; int b = t >> 8;
    const float* rb = r + b * N1 * N1;
    const int j1s = (j1 + 128) & 255;
    float acc = 0.f;
    for (int K = 1; K <= N1; ++K) {
        acc = fmaf(ss[(j1s * K) & 255], rb[(K - 1) * N1 + kk], acc);
    }
    T1[idx] = acc;
}

// DST stage 2
__global__ __launch_bounds__(256) void dst_stage2(
    const float* __restrict__ T1, const float* __restrict__ sintab,
    float* __restrict__ rhat) {
    __shared__ float ss[256];
    ss[threadIdx.x] = sintab[threadIdx.x];
    __syncthreads();
    int idx = blockIdx.x * 256 + threadIdx.x;
    int j2 = idx & 255;
    int t = idx >> 8;
    int j1 = t & 255; int b = t >> 8;
    const float* t1 = T1 + ((size_t)b * G + j1) * N1;
    const int j2s = (j2 + 128) & 255;
    float acc = 0.f;
    for (int kk = 0; kk < N1; ++kk) {
        acc = fmaf(ss[(j2s * (kk + 1)) & 255], t1[kk], acc);
    }
    rhat[idx] = acc * (-4.0f / 65536.0f);
}

// ---------------------------------------------------------------------------
// Forward composed 7x7 conv: rhat (real, 1ch) -> A (16ch complex). pk_fma.
__global__ __launch_bounds__(256) void fwd7_kernel(
    const float* __restrict__ rhat,
    const float* __restrict__ w7r, const float* __restrict__ w7i, // [b][16][49]
    float* __restrict__ yr, float* __restrict__ yi) {
    __shared__ float sW[16*49*2];
    __shared__ float sIn[22*38];
    const int b = blockIdx.y;
    const int tile = blockIdx.x;            // 8 x-tiles (32) x 16 y-tiles (16)
    const int x0 = (tile & 7) * 32;
    const int y0 = (tile >> 3) * 16;
    const int tid = threadIdx.x;
    const float* wrb = w7r + (size_t)b * 784;
    const float* wib = w7i + (size_t)b * 784;
    for (int t = tid; t < 784; t += 256) { sW[2*t] = wrb[t]; sW[2*t+1] = wib[t]; }
    const float* rb = rhat + (size_t)b * GG;
    for (int t = tid; t < 22*38; t += 256) {
        int rr = t / 38, cc = t - rr * 38;
        int gy = y0 + rr - 3, gx = x0 + cc - 3;
        bool ok = ((unsigned)gy < G) & ((unsigned)gx < G);
        sIn[t] = ok ? rb[gy * G + gx] : 0.f;
    }
    __syncthreads();
    const int tx = tid & 31;
    const int ty = tid >> 5;    // 0..7
    v2f acc0[16], acc1[16];
#pragma unroll
    for (int co = 0; co < 16; ++co) { acc0[co] = (v2f){0.f,0.f}; acc1[co] = (v2f){0.f,0.f}; }
#pragma unroll
    for (int tap = 0; tap < 49; ++tap) {
        const int dy = tap / 7, dx = tap % 7;
        v2f xx;
        xx.x = sIn[(ty + dy) * 38 + tx + dx];
        xx.y = sIn[(ty + 8 + dy) * 38 + tx + dx];
#pragma unroll
        for (int co = 0; co < 16; ++co) {
            const v2f wv = *reinterpret_cast<const v2f*>(&sW[(co*49 + tap)*2]);
            RFMA_LO(acc0[co], xx, wv);
            RFMA_HI(acc1[co], xx, wv);
        }
    }
    const size_t outB = (size_t)b * 16 * GG;
#pragma unroll
    for (int co = 0; co < 16; ++co) {
        int oy0 = y0 + ty, oy1 = y0 + ty + 8, ox = x0 + tx;
        yr[outB + (size_t)co * GG + oy0 * G + ox] = acc0[co].x;
        yi[outB + (size_t)co * GG + oy0 * G + ox] = acc0[co].y;
        yr[outB + (size_t)co * GG + oy1 * G + ox] = acc1[co].x;
        yi[outB + (size_t)co * GG + oy1 * G + ox] = acc1[co].y;
    }
}

// ---------------------------------------------------------------------------
// Adjoint composed 7x7 conv with fused theta: (A .* theta) (16ch) -> HC (1ch).
// Conflict-free 4x2 mapping + LDS dbuf + async prefetch + pk_fma compute.
__global__ __launch_bounds__(256) void adj7_kernel(
    const float* __restrict__ xr, const float* __restrict__ xi,
    const float* __restrict__ tr, const float* __restrict__ ti,
    const float* __restrict__ w7r, const float* __restrict__ w7i, // [b][16][49]
    float* __restrict__ or_, float* __restrict__ oi_,
    float* __restrict__ PTA) {
    constexpr int NPX = 38*70;          // 2660 staged pixels
    constexpr int NIT = 11;             // ceil(2660/256)
    __shared__ float sW[16*49*2];
    __shared__ float sIn[2][NPX*2];
    const int b = blockIdx.y;
    const int tile = blockIdx.x;        // 4 x-tiles (64) x 8 y-tiles (32)
    const int x0 = (tile & 3) * 64;
    const int y0 = (tile >> 2) * 32;
    const int tid = threadIdx.x;
    const float* wrb = w7r + (size_t)b * 784;
    const float* wib = w7i + (size_t)b * 784;
    for (int t = tid; t < 784; t += 256) { sW[2*t] = wrb[t]; sW[2*t+1] = wib[t]; }

    int ppos[NIT];
#pragma unroll
    for (int i = 0; i < NIT; ++i) {
        int t = tid + i*256;
        int rr = t / 70, cc = t - rr*70;
        int gy = y0 + rr - 3, gx = x0 + cc - 3;
        bool ok = (t < NPX) & ((unsigned)gy < G) & ((unsigned)gx < G);
        ppos[i] = ok ? (gy * G + gx) : -1;
    }

    const int tx = tid & 31;
    const int ty = tid >> 5;            // 0..7
    v2f acc[8];
#pragma unroll
    for (int k = 0; k < 8; ++k) acc[k] = (v2f){0.f, 0.f};

    const size_t planeB = (size_t)b * 16 * GG;
    const size_t cbase0 = ((size_t)b * 16) * 4;

    // ---- prologue: stage ci=0 into buffer 0 (with PTA extraction) -------
    {
        const float* xrc = xr + planeB;
        const float* xic = xi + planeB;
        const float* trc = tr + planeB;
        const float* tic = ti + planeB;
#pragma unroll
        for (int i = 0; i < NIT; ++i) {
            int t = tid + i*256;
            if (t >= NPX) continue;
            float hr = 0.f, hi = 0.f;
            int pp = ppos[i];
            if (pp >= 0) {
                float ar = xrc[pp], ai = xic[pp];
                float cr = trc[pp], cv = tic[pp];
                hr = fmaf(ar, cr, -ai*cv);
                hi = fmaf(ar, cv,  ai*cr);
                int gy = pp >> 8, gx = pp & 255;
                if (gy < 5)    { size_t o = ((cbase0 + 0)*5 + gy      )*256 + gx; PTA[2*o] = hr; PTA[2*o+1] = hi; }
                if (gy >= 251) { size_t o = ((cbase0 + 1)*5 + gy - 251)*256 + gx; PTA[2*o] = hr; PTA[2*o+1] = hi; }
                if (gx < 5)    { size_t o = ((cbase0 + 2)*5 + gx      )*256 + gy; PTA[2*o] = hr; PTA[2*o+1] = hi; }
                if (gx >= 251) { size_t o = ((cbase0 + 3)*5 + gx - 251)*256 + gy; PTA[2*o] = hr; PTA[2*o+1] = hi; }
            }
            sIn[0][2*t] = hr; sIn[0][2*t+1] = hi;
        }
    }
    __syncthreads();

    int cur = 0;
    for (int ci = 0; ci < 16; ++ci) {
        // ---- issue prefetch loads for ci+1 -------------------------------
        float par[NIT], pai[NIT], pcr[NIT], pcv[NIT];
        const bool havenext = (ci < 15);
        if (havenext) {
            const float* xrc = xr + planeB + (size_t)(ci+1) * GG;
            const float* xic = xi + planeB + (size_t)(ci+1) * GG;
            const float* trc = tr + planeB + (size_t)(ci+1) * GG;
            const float* tic = ti + planeB + (size_t)(ci+1) * GG;
#pragma unroll
            for (int i = 0; i < NIT; ++i) {
                int pp = ppos[i];
                if (pp >= 0) {
                    par[i] = xrc[pp]; pai[i] = xic[pp];
                    pcr[i] = trc[pp]; pcv[i] = tic[pp];
                } else { par[i] = 0.f; pai[i] = 0.f; pcr[i] = 0.f; pcv[i] = 0.f; }
            }
        }

        // ---- compute ci from sIn[cur] (pk_fma) ---------------------------
        const float* wci = &sW[ci*49*2];
        const float* bufc = &sIn[cur][0];
#pragma unroll 7
        for (int tap = 0; tap < 49; ++tap) {
            const int dy = tap / 7, dx = tap % 7;
            const v2f wv = *reinterpret_cast<const v2f*>(&wci[tap*2]);
#pragma unroll
            for (int ry = 0; ry < 4; ++ry)
#pragma unroll
                for (int cx = 0; cx < 2; ++cx) {
                    const v2f xv = *reinterpret_cast<const v2f*>(
                        &bufc[((ty + 8*ry + dy) * 70 + tx + 32*cx + dx) * 2]);
                    CFMA(acc[ry*2 + cx], xv, wv);
                }
        }

        // ---- theta-multiply + write next buffer + PTA --------------------
        if (havenext) {
            float* bufn = &sIn[cur ^ 1][0];
            const size_t cbase = ((size_t)b*16 + (ci+1)) * 4;
#pragma unroll
            for (int i = 0; i < NIT; ++i) {
                int t = tid + i*256;
                if (t >= NPX) continue;
                float hr = 0.f, hi = 0.f;
                int pp = ppos[i];
                if (pp >= 0) {
                    hr = fmaf(par[i], pcr[i], -pai[i]*pcv[i]);
                    hi = fmaf(par[i], pcv[i],  pai[i]*pcr[i]);
                    int gy = pp >> 8, gx = pp & 255;
                    if (gy < 5)    { size_t o = ((cbase + 0)*5 + gy      )*256 + gx; PTA[2*o] = hr; PTA[2*o+1] = hi; }
                    if (gy >= 251) { size_t o = ((cbase + 1)*5 + gy - 251)*256 + gx; PTA[2*o] = hr; PTA[2*o+1] = hi; }
                    if (gx < 5)    { size_t o = ((cbase + 2)*5 + gx      )*256 + gy; PTA[2*o] = hr; PTA[2*o+1] = hi; }
                    if (gx >= 251) { size_t o = ((cbase + 3)*5 + gx - 251)*256 + gy; PTA[2*o] = hr; PTA[2*o+1] = hi; }
                }
                bufn[2*t] = hr; bufn[2*t+1] = hi;
            }
        }
        __syncthreads();
        cur ^= 1;
    }

    const size_t outB = (size_t)b * GG;
#pragma unroll
    for (int ry = 0; ry < 4; ++ry)
#pragma unroll
        for (int cx = 0; cx < 2; ++cx) {
            int oy = y0 + ty + 8*ry, ox = x0 + tx + 32*cx;
            or_[outB + oy*G + ox] = acc[ry*2+cx].x;
            oi_[outB + oy*G + ox] = acc[ry*2+cx].y;
        }
}

// ---------------------------------------------------------------------------
// Strip machinery. strip s: 0=TOP, 1=BOT, 2=LEF, 3=RIG. [b][ch][s][u:4][v:256].
__device__ __forceinline__ size_t sidx(int b, int ch, int s, int u, int v) {
    return ((((size_t)b*CH + ch)*4 + s)*4 + u)*256 + v;
}
__device__ __forceinline__ void spos(int s, int u, int v, int& y, int& x) {
    y = (s == 0) ? u : (s == 1) ? 252 + u : v;
    x = (s == 2) ? u : (s == 3) ? 252 + u : v;
}

// stage 1 fwd: conv1 (w1, 1->16, real rhat) exact, all u in [0,4)
__global__ __launch_bounds__(256) void strip_fwd1(
    const float* __restrict__ rhat,
    const float* __restrict__ w1r_, const float* __restrict__ w1i_, // [b][16][9]
    float* __restrict__ S1r, float* __restrict__ S1i) {
    __shared__ float sW[16*9*2];
    const int s = blockIdx.x, b = blockIdx.y;
    for (int t = threadIdx.x; t < 144; t += 256) {
        sW[2*t] = w1r_[(size_t)b*144 + t]; sW[2*t+1] = w1i_[(size_t)b*144 + t];
    }
    __syncthreads();
    const int v = threadIdx.x;
    const float* rb = rhat + (size_t)b * GG;
    for (int u = 0; u < 4; ++u) {
        int y, x; spos(s, u, v, y, x);
        float xv[9];
#pragma unroll
        for (int dy = -1; dy <= 1; ++dy)
#pragma unroll
            for (int dx = -1; dx <= 1; ++dx) {
                int gy = y + dy, gx = x + dx;
                bool ok = ((unsigned)gy < G) & ((unsigned)gx < G);
                xv[(dy+1)*3 + dx+1] = ok ? rb[gy*G+gx] : 0.f;
            }
#pragma unroll
        for (int co = 0; co < 16; ++co) {
            float ar = 0.f, ai = 0.f;
#pragma unroll
            for (int tap = 0; tap < 9; ++tap) {
                ar = fmaf(xv[tap], sW[(co*9+tap)*2], ar);
                ai = fmaf(xv[tap], sW[(co*9+tap)*2+1], ai);
            }
            S1r[sidx(b, co, s, u, v)] = ar;
            S1i[sidx(b, co, s, u, v)] = ai;
        }
    }
}

// stage 1 adj (packed): a3-conv on packed theta.*A bands. u in [0,4). pk_fma.
__global__ __launch_bounds__(256) void strip_adj1_packed(
    const float* __restrict__ PTA,   // [b][ci][4][5][256][2]
    const float* __restrict__ wr_, const float* __restrict__ wi_, // [b][16][16][9]
    float* __restrict__ S1r, float* __restrict__ S1i) {
    __shared__ float sW[16*16*9*2];
    const int s = blockIdx.x >> 2, vt = blockIdx.x & 3, b = blockIdx.y;
    for (int t = threadIdx.x; t < 2304; t += 256) {
        sW[2*t] = wr_[(size_t)b*2304 + t]; sW[2*t+1] = wi_[(size_t)b*2304 + t];
    }
    __syncthreads();
    const int v = vt * 64 + (threadIdx.x & 63);
    const int u = threadIdx.x >> 6;           // 0..3
    const int off = (s == 1 || s == 3) ? 1 : 0;
    v2f acc[16];
#pragma unroll
    for (int co = 0; co < 16; ++co) acc[co] = (v2f){0.f, 0.f};
    for (int ci = 0; ci < 16; ++ci) {
        const float* base = PTA + ((((size_t)b*16 + ci)*4 + s)*5) * 512;
        v2f n2[9];
#pragma unroll
        for (int dy = -1; dy <= 1; ++dy)
#pragma unroll
            for (int dx = -1; dx <= 1; ++dx) {
                int pu = (s < 2) ? (u + off + dy) : (u + off + dx);
                int vp = (s < 2) ? (v + dx) : (v + dy);
                v2f val = (v2f){0.f, 0.f};
                if (((unsigned)pu < 5u) & ((unsigned)vp < 256u))
                    val = *reinterpret_cast<const v2f*>(&base[(pu*256 + vp)*2]);
                n2[(dy+1)*3+dx+1] = val;
            }
#pragma unroll
        for (int co = 0; co < 16; ++co)
#pragma unroll
            for (int tap = 0; tap < 9; ++tap) {
                const v2f wv = *reinterpret_cast<const v2f*>(&sW[((co*16+ci)*9+tap)*2]);
                CFMA(acc[co], n2[tap], wv);
            }
    }
#pragma unroll
    for (int co = 0; co < 16; ++co) {
        S1r[sidx(b, co, s, u, v)] = acc[co].x;
        S1i[sidx(b, co, s, u, v)] = acc[co].y;
    }
}

// stage 2: 16->16 conv strips->strips, u in [u0, u0+3). grid (16, cb). pk_fma.
__global__ __launch_bounds__(256) void strip_mid(
    const float* __restrict__ Ar, const float* __restrict__ Ai,
    const float* __restrict__ wr_, const float* __restrict__ wi_, // [b][16][16][9]
    float* __restrict__ Br, float* __restrict__ Bi) {
    __shared__ float sW[16*16*9*2];
    const int s = blockIdx.x >> 2, vt = blockIdx.x & 3, b = blockIdx.y;
    for (int t = threadIdx.x; t < 2304; t += 256) {
        sW[2*t] = wr_[(size_t)b*2304 + t]; sW[2*t+1] = wi_[(size_t)b*2304 + t];
    }
    __syncthreads();
    const int v = vt * 64 + (threadIdx.x & 63);
    const int uslot = threadIdx.x >> 6;
    if (uslot >= 3) return;
    const int u0 = (s == 1 || s == 3) ? 1 : 0;
    const int u = u0 + uslot;
    int y, x; spos(s, u, v, y, x);
    v2f acc[16];
#pragma unroll
    for (int co = 0; co < 16; ++co) acc[co] = (v2f){0.f, 0.f};
    for (int ci = 0; ci < 16; ++ci) {
        v2f n2[9];
#pragma unroll
        for (int dy = -1; dy <= 1; ++dy)
#pragma unroll
            for (int dx = -1; dx <= 1; ++dx) {
                int gy = y + dy, gx = x + dx;
                v2f val = (v2f){0.f, 0.f};
                if (((unsigned)gy < G) & ((unsigned)gx < G)) {
                    int up = (s < 2) ? u + dy : u + dx;
                    int vp = (s < 2) ? v + dx : v + dy;
                    size_t ix = sidx(b, ci, s, up, vp);
                    val.x = Ar[ix]; val.y = Ai[ix];
                }
                n2[(dy+1)*3+dx+1] = val;
            }
#pragma unroll
        for (int co = 0; co < 16; ++co)
#pragma unroll
            for (int tap = 0; tap < 9; ++tap) {
                const v2f wv = *reinterpret_cast<const v2f*>(&sW[((co*16+ci)*9+tap)*2]);
                CFMA(acc[co], n2[tap], wv);
            }
    }
#pragma unroll
    for (int co = 0; co < 16; ++co) {
        Br[sidx(b, co, s, u, v)] = acc[co].x;
        Bi[sidx(b, co, s, u, v)] = acc[co].y;
    }
}

// stage 3: COUT ch from strips -> overwrite band in planes, u in [u0,u0+2). pk_fma.
template<int COUT>
__global__ __launch_bounds__(256) void strip_fin(
    const float* __restrict__ Ar, const float* __restrict__ Ai,
    const float* __restrict__ wr_, const float* __restrict__ wi_, // [b][COUT][16][9]
    float* __restrict__ Or, float* __restrict__ Oi) {
    __shared__ float sW[COUT*16*9*2];
    const int s = blockIdx.x >> 2, vt = blockIdx.x & 3, b = blockIdx.y;
    for (int t = threadIdx.x; t < COUT*144; t += 256) {
        sW[2*t] = wr_[(size_t)b*COUT*144 + t]; sW[2*t+1] = wi_[(size_t)b*COUT*144 + t];
    }
    __syncthreads();
    const int v = vt * 64 + (threadIdx.x & 63);
    const int uslot = threadIdx.x >> 6;
    if (uslot >= 2) return;
    const int u0 = (s == 1 || s == 3) ? 2 : 0;
    const int u = u0 + uslot;
    int y, x; spos(s, u, v, y, x);
    v2f acc[COUT];
#pragma unroll
    for (int co = 0; co < COUT; ++co) acc[co] = (v2f){0.f, 0.f};
    for (int ci = 0; ci < 16; ++ci) {
        v2f n2[9];
#pragma unroll
        for (int dy = -1; dy <= 1; ++dy)
#pragma unroll
            for (int dx = -1; dx <= 1; ++dx) {
                int gy = y + dy, gx = x + dx;
                v2f val = (v2f){0.f, 0.f};
                if (((unsigned)gy < G) & ((unsigned)gx < G)) {
                    int up = (s < 2) ? u + dy : u + dx;
                    int vp = (s < 2) ? v + dx : v + dy;
                    size_t ix = sidx(b, ci, s, up, vp);
                    val.x = Ar[ix]; val.y = Ai[ix];
                }
                n2[(dy+1)*3+dx+1] = val;
            }
#pragma unroll
        for (int co = 0; co < COUT; ++co)
#pragma unroll
            for (int tap = 0; tap < 9; ++tap) {
                const v2f wv = *reinterpret_cast<const v2f*>(&sW[((co*16+ci)*9+tap)*2]);
                CFMA(acc[co], n2[tap], wv);
            }
    }
#pragma unroll
    for (int co = 0; co < COUT; ++co) {
        Or[((size_t)b*COUT + co)*GG + y*G + x] = acc[co].x;
        Oi[((size_t)b*COUT + co)*GG + y*G + x] = acc[co].y;
    }
}

// ---------------------------------------------------------------------------
__global__ __launch_bounds__(256) void fft_stage1(
    const float* __restrict__ hr, const float* __restrict__ hi,
    const float* __restrict__ sintab,
    float* __restrict__ Ur, float* __restrict__ Ui) {
    __shared__ float ss[256];
    ss[threadIdx.x] = sintab[threadIdx.x];
    __syncthreads();
    int idx = blockIdx.x * 256 + threadIdx.x;
    int j2 = idx & 255;
    int t = idx >> 8;
    int k1 = t % N1; int b = t / N1;
    const float* hrb = hr + (size_t)b * GG;
    const float* hib = hi + (size_t)b * GG;
    float ur = 0.f, ui = 0.f;
    for (int j1 = 0; j1 < G; ++j1) {
        int ph = (k1 * j1) & 255;
        float s = ss[ph], c = ss[(ph + 64) & 255];
        float xr = hrb[j1 * G + j2], xi = hib[j1 * G + j2];
        ur += xr * c + xi * s;
        ui += xi * c - xr * s;
    }
    Ur[idx] = ur; Ui[idx] = ui;
}

__global__ __launch_bounds__(256) void fft_stage2(
    const float* __restrict__ Ur, const float* __restrict__ Ui,
    const float* __restrict__ sintab, float* __restrict__ out, int nb) {
    __shared__ float ss[256];
    ss[threadIdx.x] = sintab[threadIdx.x];
    __syncthreads();
    int idx = blockIdx.x * 256 + threadIdx.x;
    if (idx >= nb * N1 * N1) return;
    int k2 = idx % N1;
    int t = idx / N1;
    int k1 = t % N1; int b = t / N1;
    const float* urb = Ur + ((size_t)b * N1 + k1) * G;
    const float* uib = Ui + ((size_t)b * N1 + k1) * G;
    float acc = 0.f;
    for (int j2 = 0; j2 < G; ++j2) {
        int ph = (k2 * j2) & 255;
        float s = ss[ph], c = ss[(ph + 64) & 255];
        acc += urb[j2] * c + uib[j2] * s;
    }
    out[idx] = ((k1 + k2) & 1) ? -acc : acc;
}

// ---------------------------------------------------------------------------
extern "C" void kernel_launch(void* const* d_in, const int* in_sizes, int n_in,
                              void* d_out, int out_size, void* d_ws, size_t ws_size,
                              hipStream_t stream) {
    const float* r   = (const float*)d_in[0];
    const float* w1r = (const float*)d_in[1];
    const float* w1i = (const float*)d_in[2];
    const float* w2r = (const float*)d_in[3];
    const float* w2i = (const float*)d_in[4];
    const float* w3r = (const float*)d_in[5];
    const float* w3i = (const float*)d_in[6];
    const float* wtr = (const float*)d_in[7];
    const float* wti = (const float*)d_in[8];
    float* out = (float*)d_out;

    float* ws = (float*)d_ws;
    const size_t g = (size_t)GG;

    // ---- fixed region ---------------------------------------------------
    const size_t SZ16 = (size_t)NB*CH*CH*9;   // 73728
    const size_t SZ1  = (size_t)NB*CH*9;      // 4608
    const size_t SZ5  = (size_t)NB*16*25;
    const size_t SZ7  = (size_t)NB*16*49;
    float* p = ws;
    float* SIN  = p; p += 1024;
    float* A3R = p; p += SZ16;  float* A3I = p; p += SZ16;
    float* A2R = p; p += SZ16;  float* A2I = p; p += SZ16;
    float* A1R = p; p += SZ1;   float* A1I = p; p += SZ1;
    float* C5R = p; p += SZ5;   float* C5I = p; p += SZ5;
    float* C7FR = p; p += SZ7;  float* C7FI = p; p += SZ7;
    float* Q5R = p; p += SZ5;   float* Q5I = p; p += SZ5;
    float* C7AR = p; p += SZ7;  float* C7AI = p; p += SZ7;
    const size_t extraFloats = (size_t)(p - ws);

    // ---- adaptive chunking ---------------------------------------------
    const size_t sampFloats = 32*g + g + g/2 + 2*g + 2*g + 2*g + g + g/2 + 5*g;
    size_t availFloats = ws_size / 4;
    long long usable = (long long)availFloats - (long long)extraFloats;
    int cbm = 1;
    if (usable > 0) {
        long long c = usable / (long long)sampFloats;
        cbm = (int)(c < 1 ? 1 : (c > NB ? NB : c));
    }

    float* base = ws + extraFloats;
    float* A_RE = base;
    float* A_IM = A_RE + (size_t)cbm*16*g;
    float* RHAT = A_IM + (size_t)cbm*16*g;
    float* T1D  = RHAT + (size_t)cbm*g;
    float* S1r  = T1D + (size_t)cbm*(g/2);
    float* S1i  = S1r + (size_t)cbm*g;
    float* S2r  = S1i + (size_t)cbm*g;
    float* S2i  = S2r + (size_t)cbm*g;
    float* HCr  = S2i + (size_t)cbm*g;
    float* HCi  = HCr + (size_t)cbm*g;
    float* Ur   = HCi + (size_t)cbm*g;
    float* Ui   = Ur + (size_t)cbm*(g/2);
    float* PTA  = Ui + (size_t)cbm*(g/2);      // [cb][16][4][5][256][2]

    // ---- one-time prep --------------------------------------------------
    hipLaunchKernelGGL(init_sintab, dim3(1), dim3(256), 0, stream, SIN);
    hipLaunchKernelGGL(prep_adj16, dim3((unsigned)((SZ16+255)/256)), dim3(256), 0, stream,
                       w3r, w3i, A3R, A3I);
    hipLaunchKernelGGL(prep_adj16, dim3((unsigned)((SZ16+255)/256)), dim3(256), 0, stream,
                       w2r, w2i, A2R, A2I);
    hipLaunchKernelGGL(prep_adj1,  dim3((unsigned)((SZ1+255)/256)),  dim3(256), 0, stream,
                       w1r, w1i, A1R, A1I);
    hipLaunchKernelGGL((compose_k<16,16,1,3,3>), dim3((unsigned)((NB*16*25+255)/256)), dim3(256),
                       0, stream, w2r, w2i, w1r, w1i, C5R, C5I);
    hipLaunchKernelGGL((compose_k<16,16,1,3,5>), dim3((unsigned)((NB*16*49+255)/256)), dim3(256),
                       0, stream, w3r, w3i, C5R, C5I, C7FR, C7FI);
    hipLaunchKernelGGL((compose_k<1,16,16,3,3>), dim3((unsigned)((NB*16*25+255)/256)), dim3(256),
                       0, stream, A1R, A1I, A2R, A2I, Q5R, Q5I);
    hipLaunchKernelGGL((compose_k<1,16,16,5,3>), dim3((unsigned)((NB*16*49+255)/256)), dim3(256),
                       0, stream, Q5R, Q5I, A3R, A3I, C7AR, C7AI);

    // ---- per-chunk pipeline --------------------------------------------
    for (int b0 = 0; b0 < NB; b0 += cbm) {
        const int cb = (NB - b0) < cbm ? (NB - b0) : cbm;

        const float* r_c    = r    + (size_t)b0 * N1 * N1;
        const float* w1r_c  = w1r  + (size_t)b0 * 144;
        const float* w1i_c  = w1i  + (size_t)b0 * 144;
        const float* w2r_c  = w2r  + (size_t)b0 * 2304;
        const float* w2i_c  = w2i  + (size_t)b0 * 2304;
        const float* w3r_c  = w3r  + (size_t)b0 * 2304;
        const float* w3i_c  = w3i  + (size_t)b0 * 2304;
        const float* a3r_c  = A3R  + (size_t)b0 * 2304;
        const float* a3i_c  = A3I  + (size_t)b0 * 2304;
        const float* a2r_c  = A2R  + (size_t)b0 * 2304;
        const float* a2i_c  = A2I  + (size_t)b0 * 2304;
        const float* a1r_c  = A1R  + (size_t)b0 * 144;
        const float* a1i_c  = A1I  + (size_t)b0 * 144;
        const float* c7fr_c = C7FR + (size_t)b0 * 784;
        const float* c7fi_c = C7FI + (size_t)b0 * 784;
        const float* c7ar_c = C7AR + (size_t)b0 * 784;
        const float* c7ai_c = C7AI + (size_t)b0 * 784;
        const float* wtr_c  = wtr  + (size_t)b0 * CH * GG;
        const float* wti_c  = wti  + (size_t)b0 * CH * GG;
        float* out_c = out + (size_t)b0 * N1 * N1;

        hipLaunchKernelGGL(dst_stage1, dim3((cb*G*N1 + 255)/256), dim3(256), 0, stream,
                           r_c, SIN, T1D, cb);
        hipLaunchKernelGGL(dst_stage2, dim3(cb*256), dim3(256), 0, stream,
                           T1D, SIN, RHAT);

        hipLaunchKernelGGL(fwd7_kernel, dim3(128, cb), dim3(256), 0, stream,
                           RHAT, c7fr_c, c7fi_c, A_RE, A_IM);
        hipLaunchKernelGGL(strip_fwd1, dim3(4, cb), dim3(256), 0, stream,
                           RHAT, w1r_c, w1i_c, S1r, S1i);
        hipLaunchKernelGGL(strip_mid, dim3(16, cb), dim3(256), 0, stream,
                           S1r, S1i, w2r_c, w2i_c, S2r, S2i);
        hipLaunchKernelGGL((strip_fin<16>), dim3(16, cb), dim3(256), 0, stream,
                           S2r, S2i, w3r_c, w3i_c, A_RE, A_IM);

        hipLaunchKernelGGL(adj7_kernel, dim3(32, cb), dim3(256), 0, stream,
                           A_RE, A_IM, wtr_c, wti_c, c7ar_c, c7ai_c, HCr, HCi, PTA);
        hipLaunchKernelGGL(strip_adj1_packed, dim3(16, cb), dim3(256), 0, stream,
                           PTA, a3r_c, a3i_c, S1r, S1i);
        hipLaunchKernelGGL(strip_mid, dim3(16, cb), dim3(256), 0, stream,
                           S1r, S1i, a2r_c, a2i_c, S2r, S2i);
        hipLaunchKernelGGL((strip_fin<1>), dim3(16, cb), dim3(256), 0, stream,
                           S2r, S2i, a1r_c, a1i_c, HCr, HCi);

        hipLaunchKernelGGL(fft_stage1, dim3(cb*N1), dim3(256), 0, stream,
                           HCr, HCi, SIN, Ur, Ui);
        hipLaunchKernelGGL(fft_stage2, dim3((cb*N1*N1 + 255)/256), dim3(256), 0, stream,
                           Ur, Ui, SIN, out_c, cb);
    }
}

// Round 8
// 983.706 us; speedup vs baseline: 1.5049x; 1.0594x over previous
//
#include <hip/hip_runtime.h>
#include <hip/hip_bf16.h>
#include <math.h>

#define NB 32
#define CH 16
#define N1 127
#define G 256
#define GG (G*G)

typedef float v2f __attribute__((ext_vector_type(2)));

// acc(lo=Re,hi=Im) += complex(x) * complex(w);  x=(xr,xi), w=(wr,wi)
#define CFMA(acc, x, w) do { \
  asm("v_pk_fma_f32 %0, %1, %2, %0 op_sel:[0,0,0] op_sel_hi:[0,1,1]" \
      : "+v"(acc) : "v"(x), "v"(w)); \
  asm("v_pk_fma_f32 %0, %1, %2, %0 op_sel:[1,1,0] op_sel_hi:[1,0,1] neg_lo:[0,1,0]" \
      : "+v"(acc) : "v"(x), "v"(w)); \
} while (0)
// acc += real(x.lo) * complex(w)
#define RFMA_LO(acc, x, w) \
  asm("v_pk_fma_f32 %0, %1, %2, %0 op_sel:[0,0,0] op_sel_hi:[0,1,1]" \
      : "+v"(acc) : "v"(x), "v"(w))
// acc += real(x.hi) * complex(w)
#define RFMA_HI(acc, x, w) \
  asm("v_pk_fma_f32 %0, %1, %2, %0 op_sel:[1,0,0] op_sel_hi:[1,1,1]" \
      : "+v"(acc) : "v"(x), "v"(w))

// ---------------------------------------------------------------------------
__global__ void init_sintab(float* __restrict__ sintab) {
    int t = threadIdx.x;
    sintab[t] = sinf(6.28318530717958647692f * (float)t / 256.0f);
}

// adj(w)[b,a,c,ky,kx] = conj(w[b,c,a,kx,ky])
__global__ __launch_bounds__(256) void prep_adj16(
    const float* __restrict__ wr, const float* __restrict__ wi,
    float* __restrict__ our, float* __restrict__ oui) {
    int idx = blockIdx.x * 256 + threadIdx.x;
    if (idx >= NB*CH*CH*9) return;
    int tap = idx % 9; int t = idx / 9;
    int c = t % CH; t /= CH;
    int a = t % CH; int b = t / CH;
    int ky = tap / 3, kx = tap % 3;
    int src = ((b*CH + c)*CH + a)*9 + kx*3 + ky;
    our[idx] = wr[src];
    oui[idx] = -wi[src];
}

__global__ __launch_bounds__(256) void prep_adj1(
    const float* __restrict__ wr, const float* __restrict__ wi,
    float* __restrict__ our, float* __restrict__ oui) {
    int idx = blockIdx.x * 256 + threadIdx.x;
    if (idx >= NB*CH*9) return;
    int tap = idx % 9; int t = idx / 9;
    int c = t % CH; int b = t / CH;
    int ky = tap / 3, kx = tap % 3;
    int src = (b*CH + c)*9 + kx*3 + ky;
    our[idx] = wr[src];
    oui[idx] = -wi[src];
}

// ---------------------------------------------------------------------------
// Kernel-tap composition: R[t] = sum_{a+b=t} P[a] Q[b]  (complex), contract CM
template<int CO, int CM, int CI, int KP, int KQ>
__global__ __launch_bounds__(256) void compose_k(
    const float* __restrict__ Pr, const float* __restrict__ Pi,
    const float* __restrict__ Qr, const float* __restrict__ Qi,
    float* __restrict__ Rr, float* __restrict__ Ri) {
    constexpr int T = KP + KQ - 1;
    int idx = blockIdx.x * 256 + threadIdx.x;
    if (idx >= NB*CO*CI*T*T) return;
    int txp = idx % T; int t = idx / T;
    int typ = t % T; t /= T;
    int ci = t % CI; t /= CI;
    int co = t % CO; int b = t / CO;
    float ar = 0.f, ai = 0.f;
    for (int m = 0; m < CM; ++m) {
        const float* pr = Pr + (((size_t)b*CO + co)*CM + m)*KP*KP;
        const float* pi = Pi + (((size_t)b*CO + co)*CM + m)*KP*KP;
        const float* qr = Qr + (((size_t)b*CM + m)*CI + ci)*KQ*KQ;
        const float* qi = Qi + (((size_t)b*CM + m)*CI + ci)*KQ*KQ;
        for (int ay = 0; ay < KP; ++ay) {
            int by = typ - ay; if (by < 0 || by >= KQ) continue;
            for (int ax = 0; ax < KP; ++ax) {
                int bx = txp - ax; if (bx < 0 || bx >= KQ) continue;
                float prr = pr[ay*KP+ax], pii = pi[ay*KP+ax];
                float qrr = qr[by*KQ+bx], qii = qi[by*KQ+bx];
                ar += prr*qrr - pii*qii;
                ai += prr*qii + pii*qrr;
            }
        }
    }
    Rr[idx] = ar; Ri[idx] = ai;
}

// ---------------------------------------------------------------------------
// DST stage 1  ((-1)^K folded into sin index)
__global__ __launch_bounds__(256) void dst_stage1(
    const float* __restrict__ r, const float* __restrict__ sintab,
    float* __restrict__ T1, int nb) {
    __shared__ float ss[256];
    ss[threadIdx.x] = sintab[threadIdx.x];
    __syncthreads();
    int idx = blockIdx.x * 256 + threadIdx.x;
    if (idx >= nb*G*N1) return;
    int kk = idx % N1;
    int t = idx / N1;
    int j1 = t & 255; int b = t >> 8;
    const float* rb = r + b * N1 * N1;
    const int j1s = (j1 + 128) & 255;
    float acc = 0.f;
    for (int K = 1; K <= N1; ++K) {
        acc = fmaf(ss[(j1s * K) & 255], rb[(K - 1) * N1 + kk], acc);
    }
    T1[idx] = acc;
}

// DST stage 2
__global__ __launch_bounds__(256) void dst_stage2(
    const float* __restrict__ T1, const float* __restrict__ sintab,
    float* __restrict__ rhat) {
    __shared__ float ss[256];
    ss[threadIdx.x] = sintab[threadIdx.x];
    __syncthreads();
    int idx = blockIdx.x * 256 + threadIdx.x;
    int j2 = idx & 255;
    int t = idx >> 8;
    int j1 = t & 255; int b = t >> 8;
    const float* t1 = T1 + ((size_t)b * G + j1) * N1;
    const int j2s = (j2 + 128) & 255;
    float acc = 0.f;
    for (int kk = 0; kk < N1; ++kk) {
        acc = fmaf(ss[(j2s * (kk + 1)) & 255], t1[kk], acc);
    }
    rhat[idx] = acc * (-4.0f / 65536.0f);
}

// ---------------------------------------------------------------------------
// Forward composed 7x7 conv: rhat (real, 1ch) -> A (16ch complex). pk_fma.
__global__ __launch_bounds__(256) void fwd7_kernel(
    const float* __restrict__ rhat,
    const float* __restrict__ w7r, const float* __restrict__ w7i, // [b][16][49]
    float* __restrict__ yr, float* __restrict__ yi) {
    __shared__ float sW[16*49*2];
    __shared__ float sIn[22*38];
    const int b = blockIdx.y;
    const int tile = blockIdx.x;            // 8 x-tiles (32) x 16 y-tiles (16)
    const int x0 = (tile & 7) * 32;
    const int y0 = (tile >> 3) * 16;
    const int tid = threadIdx.x;
    const float* wrb = w7r + (size_t)b * 784;
    const float* wib = w7i + (size_t)b * 784;
    for (int t = tid; t < 784; t += 256) { sW[2*t] = wrb[t]; sW[2*t+1] = wib[t]; }
    const float* rb = rhat + (size_t)b * GG;
    for (int t = tid; t < 22*38; t += 256) {
        int rr = t / 38, cc = t - rr * 38;
        int gy = y0 + rr - 3, gx = x0 + cc - 3;
        bool ok = ((unsigned)gy < G) & ((unsigned)gx < G);
        sIn[t] = ok ? rb[gy * G + gx] : 0.f;
    }
    __syncthreads();
    const int tx = tid & 31;
    const int ty = tid >> 5;    // 0..7
    v2f acc0[16], acc1[16];
#pragma unroll
    for (int co = 0; co < 16; ++co) { acc0[co] = (v2f){0.f,0.f}; acc1[co] = (v2f){0.f,0.f}; }
#pragma unroll
    for (int tap = 0; tap < 49; ++tap) {
        const int dy = tap / 7, dx = tap % 7;
        v2f xx;
        xx.x = sIn[(ty + dy) * 38 + tx + dx];
        xx.y = sIn[(ty + 8 + dy) * 38 + tx + dx];
#pragma unroll
        for (int co = 0; co < 16; ++co) {
            const v2f wv = *reinterpret_cast<const v2f*>(&sW[(co*49 + tap)*2]);
            RFMA_LO(acc0[co], xx, wv);
            RFMA_HI(acc1[co], xx, wv);
        }
    }
    const size_t outB = (size_t)b * 16 * GG;
#pragma unroll
    for (int co = 0; co < 16; ++co) {
        int oy0 = y0 + ty, oy1 = y0 + ty + 8, ox = x0 + tx;
        yr[outB + (size_t)co * GG + oy0 * G + ox] = acc0[co].x;
        yi[outB + (size_t)co * GG + oy0 * G + ox] = acc0[co].y;
        yr[outB + (size_t)co * GG + oy1 * G + ox] = acc1[co].x;
        yi[outB + (size_t)co * GG + oy1 * G + ox] = acc1[co].y;
    }
}

// ---------------------------------------------------------------------------
// Adjoint composed 7x7 conv with fused theta: (A .* theta) (16ch) -> HC (1ch).
// Register-window mapping: thread owns 8 CONSECUTIVE outputs in one row
// (ty=tid>>3 in 0..31, txi=tid&7). Per (ci,dy): 7 aligned ds_read_b128 load a
// 14-float2 window; 56 pk-CFMA consume it. LDS bytes cut 4x vs per-tap reads.
// LDS dbuf + async prefetch + PTA extraction unchanged.
__global__ __launch_bounds__(256) void adj7_kernel(
    const float* __restrict__ xr, const float* __restrict__ xi,
    const float* __restrict__ tr, const float* __restrict__ ti,
    const float* __restrict__ w7r, const float* __restrict__ w7i, // [b][16][49]
    float* __restrict__ or_, float* __restrict__ oi_,
    float* __restrict__ PTA) {
    constexpr int NPX = 38*70;          // 2660 staged pixels
    constexpr int NIT = 11;             // ceil(2660/256)
    __shared__ float sW[16*49*2];
    __shared__ float sIn[2][NPX*2];
    const int b = blockIdx.y;
    const int tile = blockIdx.x;        // 4 x-tiles (64) x 8 y-tiles (32)
    const int x0 = (tile & 3) * 64;
    const int y0 = (tile >> 2) * 32;
    const int tid = threadIdx.x;
    const float* wrb = w7r + (size_t)b * 784;
    const float* wib = w7i + (size_t)b * 784;
    for (int t = tid; t < 784; t += 256) { sW[2*t] = wrb[t]; sW[2*t+1] = wib[t]; }

    int ppos[NIT];
#pragma unroll
    for (int i = 0; i < NIT; ++i) {
        int t = tid + i*256;
        int rr = t / 70, cc = t - rr*70;
        int gy = y0 + rr - 3, gx = x0 + cc - 3;
        bool ok = (t < NPX) & ((unsigned)gy < G) & ((unsigned)gx < G);
        ppos[i] = ok ? (gy * G + gx) : -1;
    }

    const int ty  = tid >> 3;           // 0..31: output row
    const int txi = tid & 7;            // output cols x0 + 8*txi .. +7
    v2f acc[8];
#pragma unroll
    for (int k = 0; k < 8; ++k) acc[k] = (v2f){0.f, 0.f};

    const size_t planeB = (size_t)b * 16 * GG;
    const size_t cbase0 = ((size_t)b * 16) * 4;

    // ---- prologue: stage ci=0 into buffer 0 (with PTA extraction) -------
    {
        const float* xrc = xr + planeB;
        const float* xic = xi + planeB;
        const float* trc = tr + planeB;
        const float* tic = ti + planeB;
#pragma unroll
        for (int i = 0; i < NIT; ++i) {
            int t = tid + i*256;
            if (t >= NPX) continue;
            float hr = 0.f, hi = 0.f;
            int pp = ppos[i];
            if (pp >= 0) {
                float ar = xrc[pp], ai = xic[pp];
                float cr = trc[pp], cv = tic[pp];
                hr = fmaf(ar, cr, -ai*cv);
                hi = fmaf(ar, cv,  ai*cr);
                int gy = pp >> 8, gx = pp & 255;
                if (gy < 5)    { size_t o = ((cbase0 + 0)*5 + gy      )*256 + gx; PTA[2*o] = hr; PTA[2*o+1] = hi; }
                if (gy >= 251) { size_t o = ((cbase0 + 1)*5 + gy - 251)*256 + gx; PTA[2*o] = hr; PTA[2*o+1] = hi; }
                if (gx < 5)    { size_t o = ((cbase0 + 2)*5 + gx      )*256 + gy; PTA[2*o] = hr; PTA[2*o+1] = hi; }
                if (gx >= 251) { size_t o = ((cbase0 + 3)*5 + gx - 251)*256 + gy; PTA[2*o] = hr; PTA[2*o+1] = hi; }
            }
            sIn[0][2*t] = hr; sIn[0][2*t+1] = hi;
        }
    }
    __syncthreads();

    int cur = 0;
    for (int ci = 0; ci < 16; ++ci) {
        // ---- issue prefetch loads for ci+1 -------------------------------
        float par[NIT], pai[NIT], pcr[NIT], pcv[NIT];
        const bool havenext = (ci < 15);
        if (havenext) {
            const float* xrc = xr + planeB + (size_t)(ci+1) * GG;
            const float* xic = xi + planeB + (size_t)(ci+1) * GG;
            const float* trc = tr + planeB + (size_t)(ci+1) * GG;
            const float* tic = ti + planeB + (size_t)(ci+1) * GG;
#pragma unroll
            for (int i = 0; i < NIT; ++i) {
                int pp = ppos[i];
                if (pp >= 0) {
                    par[i] = xrc[pp]; pai[i] = xic[pp];
                    pcr[i] = trc[pp]; pcv[i] = tic[pp];
                } else { par[i] = 0.f; pai[i] = 0.f; pcr[i] = 0.f; pcv[i] = 0.f; }
            }
        }

        // ---- compute ci from sIn[cur]: window loads + pk_fma -------------
        const float* wci = &sW[ci*49*2];
        const float* bufc = &sIn[cur][0];
#pragma unroll
        for (int dy = 0; dy < 7; ++dy) {
            const float* rowp = &bufc[((ty + dy) * 70 + txi * 8) * 2];
            v2f win[14];
#pragma unroll
            for (int q = 0; q < 7; ++q) {
                const float4 vv = *reinterpret_cast<const float4*>(&rowp[q*4]);
                win[2*q]   = (v2f){vv.x, vv.y};
                win[2*q+1] = (v2f){vv.z, vv.w};
            }
#pragma unroll
            for (int dx = 0; dx < 7; ++dx) {
                const v2f wv = *reinterpret_cast<const v2f*>(&wci[(dy*7+dx)*2]);
#pragma unroll
                for (int k = 0; k < 8; ++k)
                    CFMA(acc[k], win[k+dx], wv);
            }
        }

        // ---- theta-multiply + write next buffer + PTA --------------------
        if (havenext) {
            float* bufn = &sIn[cur ^ 1][0];
            const size_t cbase = ((size_t)b*16 + (ci+1)) * 4;
#pragma unroll
            for (int i = 0; i < NIT; ++i) {
                int t = tid + i*256;
                if (t >= NPX) continue;
                float hr = 0.f, hi = 0.f;
                int pp = ppos[i];
                if (pp >= 0) {
                    hr = fmaf(par[i], pcr[i], -pai[i]*pcv[i]);
                    hi = fmaf(par[i], pcv[i],  pai[i]*pcr[i]);
                    int gy = pp >> 8, gx = pp & 255;
                    if (gy < 5)    { size_t o = ((cbase + 0)*5 + gy      )*256 + gx; PTA[2*o] = hr; PTA[2*o+1] = hi; }
                    if (gy >= 251) { size_t o = ((cbase + 1)*5 + gy - 251)*256 + gx; PTA[2*o] = hr; PTA[2*o+1] = hi; }
                    if (gx < 5)    { size_t o = ((cbase + 2)*5 + gx      )*256 + gy; PTA[2*o] = hr; PTA[2*o+1] = hi; }
                    if (gx >= 251) { size_t o = ((cbase + 3)*5 + gx - 251)*256 + gy; PTA[2*o] = hr; PTA[2*o+1] = hi; }
                }
                bufn[2*t] = hr; bufn[2*t+1] = hi;
            }
        }
        __syncthreads();
        cur ^= 1;
    }

    const size_t outB = (size_t)b * GG;
    const int oy = y0 + ty, ox = x0 + txi * 8;
    float4 r0 = make_float4(acc[0].x, acc[1].x, acc[2].x, acc[3].x);
    float4 r1 = make_float4(acc[4].x, acc[5].x, acc[6].x, acc[7].x);
    float4 i0 = make_float4(acc[0].y, acc[1].y, acc[2].y, acc[3].y);
    float4 i1 = make_float4(acc[4].y, acc[5].y, acc[6].y, acc[7].y);
    *reinterpret_cast<float4*>(&or_[outB + oy*G + ox])     = r0;
    *reinterpret_cast<float4*>(&or_[outB + oy*G + ox + 4]) = r1;
    *reinterpret_cast<float4*>(&oi_[outB + oy*G + ox])     = i0;
    *reinterpret_cast<float4*>(&oi_[outB + oy*G + ox + 4]) = i1;
}

// ---------------------------------------------------------------------------
// Strip machinery. strip s: 0=TOP, 1=BOT, 2=LEF, 3=RIG. [b][ch][s][u:4][v:256].
__device__ __forceinline__ size_t sidx(int b, int ch, int s, int u, int v) {
    return ((((size_t)b*CH + ch)*4 + s)*4 + u)*256 + v;
}
__device__ __forceinline__ void spos(int s, int u, int v, int& y, int& x) {
    y = (s == 0) ? u : (s == 1) ? 252 + u : v;
    x = (s == 2) ? u : (s == 3) ? 252 + u : v;
}

// stage 1 fwd: conv1 (w1, 1->16, real rhat) exact, all u in [0,4)
__global__ __launch_bounds__(256) void strip_fwd1(
    const float* __restrict__ rhat,
    const float* __restrict__ w1r_, const float* __restrict__ w1i_, // [b][16][9]
    float* __restrict__ S1r, float* __restrict__ S1i) {
    __shared__ float sW[16*9*2];
    const int s = blockIdx.x, b = blockIdx.y;
    for (int t = threadIdx.x; t < 144; t += 256) {
        sW[2*t] = w1r_[(size_t)b*144 + t]; sW[2*t+1] = w1i_[(size_t)b*144 + t];
    }
    __syncthreads();
    const int v = threadIdx.x;
    const float* rb = rhat + (size_t)b * GG;
    for (int u = 0; u < 4; ++u) {
        int y, x; spos(s, u, v, y, x);
        float xv[9];
#pragma unroll
        for (int dy = -1; dy <= 1; ++dy)
#pragma unroll
            for (int dx = -1; dx <= 1; ++dx) {
                int gy = y + dy, gx = x + dx;
                bool ok = ((unsigned)gy < G) & ((unsigned)gx < G);
                xv[(dy+1)*3 + dx+1] = ok ? rb[gy*G+gx] : 0.f;
            }
#pragma unroll
        for (int co = 0; co < 16; ++co) {
            float ar = 0.f, ai = 0.f;
#pragma unroll
            for (int tap = 0; tap < 9; ++tap) {
                ar = fmaf(xv[tap], sW[(co*9+tap)*2], ar);
                ai = fmaf(xv[tap], sW[(co*9+tap)*2+1], ai);
            }
            S1r[sidx(b, co, s, u, v)] = ar;
            S1i[sidx(b, co, s, u, v)] = ai;
        }
    }
}

// stage 1 adj (packed): a3-conv on packed theta.*A bands. u in [0,4). pk_fma.
__global__ __launch_bounds__(256) void strip_adj1_packed(
    const float* __restrict__ PTA,   // [b][ci][4][5][256][2]
    const float* __restrict__ wr_, const float* __restrict__ wi_, // [b][16][16][9]
    float* __restrict__ S1r, float* __restrict__ S1i) {
    __shared__ float sW[16*16*9*2];
    const int s = blockIdx.x >> 2, vt = blockIdx.x & 3, b = blockIdx.y;
    for (int t = threadIdx.x; t < 2304; t += 256) {
        sW[2*t] = wr_[(size_t)b*2304 + t]; sW[2*t+1] = wi_[(size_t)b*2304 + t];
    }
    __syncthreads();
    const int v = vt * 64 + (threadIdx.x & 63);
    const int u = threadIdx.x >> 6;           // 0..3
    const int off = (s == 1 || s == 3) ? 1 : 0;
    v2f acc[16];
#pragma unroll
    for (int co = 0; co < 16; ++co) acc[co] = (v2f){0.f, 0.f};
    for (int ci = 0; ci < 16; ++ci) {
        const float* base = PTA + ((((size_t)b*16 + ci)*4 + s)*5) * 512;
        v2f n2[9];
#pragma unroll
        for (int dy = -1; dy <= 1; ++dy)
#pragma unroll
            for (int dx = -1; dx <= 1; ++dx) {
                int pu = (s < 2) ? (u + off + dy) : (u + off + dx);
                int vp = (s < 2) ? (v + dx) : (v + dy);
                v2f val = (v2f){0.f, 0.f};
                if (((unsigned)pu < 5u) & ((unsigned)vp < 256u))
                    val = *reinterpret_cast<const v2f*>(&base[(pu*256 + vp)*2]);
                n2[(dy+1)*3+dx+1] = val;
            }
#pragma unroll
        for (int co = 0; co < 16; ++co)
#pragma unroll
            for (int tap = 0; tap < 9; ++tap) {
                const v2f wv = *reinterpret_cast<const v2f*>(&sW[((co*16+ci)*9+tap)*2]);
                CFMA(acc[co], n2[tap], wv);
            }
    }
#pragma unroll
    for (int co = 0; co < 16; ++co) {
        S1r[sidx(b, co, s, u, v)] = acc[co].x;
        S1i[sidx(b, co, s, u, v)] = acc[co].y;
    }
}

// stage 2: 16->16 conv strips->strips, u in [u0, u0+3). grid (16, cb). pk_fma.
__global__ __launch_bounds__(256) void strip_mid(
    const float* __restrict__ Ar, const float* __restrict__ Ai,
    const float* __restrict__ wr_, const float* __restrict__ wi_, // [b][16][16][9]
    float* __restrict__ Br, float* __restrict__ Bi) {
    __shared__ float sW[16*16*9*2];
    const int s = blockIdx.x >> 2, vt = blockIdx.x & 3, b = blockIdx.y;
    for (int t = threadIdx.x; t < 2304; t += 256) {
        sW[2*t] = wr_[(size_t)b*2304 + t]; sW[2*t+1] = wi_[(size_t)b*2304 + t];
    }
    __syncthreads();
    const int v = vt * 64 + (threadIdx.x & 63);
    const int uslot = threadIdx.x >> 6;
    if (uslot >= 3) return;
    const int u0 = (s == 1 || s == 3) ? 1 : 0;
    const int u = u0 + uslot;
    int y, x; spos(s, u, v, y, x);
    v2f acc[16];
#pragma unroll
    for (int co = 0; co < 16; ++co) acc[co] = (v2f){0.f, 0.f};
    for (int ci = 0; ci < 16; ++ci) {
        v2f n2[9];
#pragma unroll
        for (int dy = -1; dy <= 1; ++dy)
#pragma unroll
            for (int dx = -1; dx <= 1; ++dx) {
                int gy = y + dy, gx = x + dx;
                v2f val = (v2f){0.f, 0.f};
                if (((unsigned)gy < G) & ((unsigned)gx < G)) {
                    int up = (s < 2) ? u + dy : u + dx;
                    int vp = (s < 2) ? v + dx : v + dy;
                    size_t ix = sidx(b, ci, s, up, vp);
                    val.x = Ar[ix]; val.y = Ai[ix];
                }
                n2[(dy+1)*3+dx+1] = val;
            }
#pragma unroll
        for (int co = 0; co < 16; ++co)
#pragma unroll
            for (int tap = 0; tap < 9; ++tap) {
                const v2f wv = *reinterpret_cast<const v2f*>(&sW[((co*16+ci)*9+tap)*2]);
                CFMA(acc[co], n2[tap], wv);
            }
    }
#pragma unroll
    for (int co = 0; co < 16; ++co) {
        Br[sidx(b, co, s, u, v)] = acc[co].x;
        Bi[sidx(b, co, s, u, v)] = acc[co].y;
    }
}

// stage 3: COUT ch from strips -> overwrite band in planes, u in [u0,u0+2). pk_fma.
template<int COUT>
__global__ __launch_bounds__(256) void strip_fin(
    const float* __restrict__ Ar, const float* __restrict__ Ai,
    const float* __restrict__ wr_, const float* __restrict__ wi_, // [b][COUT][16][9]
    float* __restrict__ Or, float* __restrict__ Oi) {
    __shared__ float sW[COUT*16*9*2];
    const int s = blockIdx.x >> 2, vt = blockIdx.x & 3, b = blockIdx.y;
    for (int t = threadIdx.x; t < COUT*144; t += 256) {
        sW[2*t] = wr_[(size_t)b*COUT*144 + t]; sW[2*t+1] = wi_[(size_t)b*COUT*144 + t];
    }
    __syncthreads();
    const int v = vt * 64 + (threadIdx.x & 63);
    const int uslot = threadIdx.x >> 6;
    if (uslot >= 2) return;
    const int u0 = (s == 1 || s == 3) ? 2 : 0;
    const int u = u0 + uslot;
    int y, x; spos(s, u, v, y, x);
    v2f acc[COUT];
#pragma unroll
    for (int co = 0; co < COUT; ++co) acc[co] = (v2f){0.f, 0.f};
    for (int ci = 0; ci < 16; ++ci) {
        v2f n2[9];
#pragma unroll
        for (int dy = -1; dy <= 1; ++dy)
#pragma unroll
            for (int dx = -1; dx <= 1; ++dx) {
                int gy = y + dy, gx = x + dx;
                v2f val = (v2f){0.f, 0.f};
                if (((unsigned)gy < G) & ((unsigned)gx < G)) {
                    int up = (s < 2) ? u + dy : u + dx;
                    int vp = (s < 2) ? v + dx : v + dy;
                    size_t ix = sidx(b, ci, s, up, vp);
                    val.x = Ar[ix]; val.y = Ai[ix];
                }
                n2[(dy+1)*3+dx+1] = val;
            }
#pragma unroll
        for (int co = 0; co < COUT; ++co)
#pragma unroll
            for (int tap = 0; tap < 9; ++tap) {
                const v2f wv = *reinterpret_cast<const v2f*>(&sW[((co*16+ci)*9+tap)*2]);
                CFMA(acc[co], n2[tap], wv);
            }
    }
#pragma unroll
    for (int co = 0; co < COUT; ++co) {
        Or[((size_t)b*COUT + co)*GG + y*G + x] = acc[co].x;
        Oi[((size_t)b*COUT + co)*GG + y*G + x] = acc[co].y;
    }
}

// ---------------------------------------------------------------------------
__global__ __launch_bounds__(256) void fft_stage1(
    const float* __restrict__ hr, const float* __restrict__ hi,
    const float* __restrict__ sintab,
    float* __restrict__ Ur, float* __restrict__ Ui) {
    __shared__ float ss[256];
    ss[threadIdx.x] = sintab[threadIdx.x];
    __syncthreads();
    int idx = blockIdx.x * 256 + threadIdx.x;
    int j2 = idx & 255;
    int t = idx >> 8;
    int k1 = t % N1; int b = t / N1;
    const float* hrb = hr + (size_t)b * GG;
    const float* hib = hi + (size_t)b * GG;
    float ur = 0.f, ui = 0.f;
    for (int j1 = 0; j1 < G; ++j1) {
        int ph = (k1 * j1) & 255;
        float s = ss[ph], c = ss[(ph + 64) & 255];
        float xr = hrb[j1 * G + j2], xi = hib[j1 * G + j2];
        ur += xr * c + xi * s;
        ui += xi * c - xr * s;
    }
    Ur[idx] = ur; Ui[idx] = ui;
}

__global__ __launch_bounds__(256) void fft_stage2(
    const float* __restrict__ Ur, const float* __restrict__ Ui,
    const float* __restrict__ sintab, float* __restrict__ out, int nb) {
    __shared__ float ss[256];
    ss[threadIdx.x] = sintab[threadIdx.x];
    __syncthreads();
    int idx = blockIdx.x * 256 + threadIdx.x;
    if (idx >= nb * N1 * N1) return;
    int k2 = idx % N1;
    int t = idx / N1;
    int k1 = t % N1; int b = t / N1;
    const float* urb = Ur + ((size_t)b * N1 + k1) * G;
    const float* uib = Ui + ((size_t)b * N1 + k1) * G;
    float acc = 0.f;
    for (int j2 = 0; j2 < G; ++j2) {
        int ph = (k2 * j2) & 255;
        float s = ss[ph], c = ss[(ph + 64) & 255];
        acc += urb[j2] * c + uib[j2] * s;
    }
    out[idx] = ((k1 + k2) & 1) ? -acc : acc;
}

// ---------------------------------------------------------------------------
extern "C" void kernel_launch(void* const* d_in, const int* in_sizes, int n_in,
                              void* d_out, int out_size, void* d_ws, size_t ws_size,
                              hipStream_t stream) {
    const float* r   = (const float*)d_in[0];
    const float* w1r = (const float*)d_in[1];
    const float* w1i = (const float*)d_in[2];
    const float* w2r = (const float*)d_in[3];
    const float* w2i = (const float*)d_in[4];
    const float* w3r = (const float*)d_in[5];
    const float* w3i = (const float*)d_in[6];
    const float* wtr = (const float*)d_in[7];
    const float* wti = (const float*)d_in[8];
    float* out = (float*)d_out;

    float* ws = (float*)d_ws;
    const size_t g = (size_t)GG;

    // ---- fixed region ---------------------------------------------------
    const size_t SZ16 = (size_t)NB*CH*CH*9;   // 73728
    const size_t SZ1  = (size_t)NB*CH*9;      // 4608
    const size_t SZ5  = (size_t)NB*16*25;
    const size_t SZ7  = (size_t)NB*16*49;
    float* p = ws;
    float* SIN  = p; p += 1024;
    float* A3R = p; p += SZ16;  float* A3I = p; p += SZ16;
    float* A2R = p; p += SZ16;  float* A2I = p; p += SZ16;
    float* A1R = p; p += SZ1;   float* A1I = p; p += SZ1;
    float* C5R = p; p += SZ5;   float* C5I = p; p += SZ5;
    float* C7FR = p; p += SZ7;  float* C7FI = p; p += SZ7;
    float* Q5R = p; p += SZ5;   float* Q5I = p; p += SZ5;
    float* C7AR = p; p += SZ7;  float* C7AI = p; p += SZ7;
    const size_t extraFloats = (size_t)(p - ws);

    // ---- adaptive chunking ---------------------------------------------
    const size_t sampFloats = 32*g + g + g/2 + 2*g + 2*g + 2*g + g + g/2 + 5*g;
    size_t availFloats = ws_size / 4;
    long long usable = (long long)availFloats - (long long)extraFloats;
    int cbm = 1;
    if (usable > 0) {
        long long c = usable / (long long)sampFloats;
        cbm = (int)(c < 1 ? 1 : (c > NB ? NB : c));
    }

    float* base = ws + extraFloats;
    float* A_RE = base;
    float* A_IM = A_RE + (size_t)cbm*16*g;
    float* RHAT = A_IM + (size_t)cbm*16*g;
    float* T1D  = RHAT + (size_t)cbm*g;
    float* S1r  = T1D + (size_t)cbm*(g/2);
    float* S1i  = S1r + (size_t)cbm*g;
    float* S2r  = S1i + (size_t)cbm*g;
    float* S2i  = S2r + (size_t)cbm*g;
    float* HCr  = S2i + (size_t)cbm*g;
    float* HCi  = HCr + (size_t)cbm*g;
    float* Ur   = HCi + (size_t)cbm*g;
    float* Ui   = Ur + (size_t)cbm*(g/2);
    float* PTA  = Ui + (size_t)cbm*(g/2);      // [cb][16][4][5][256][2]

    // ---- one-time prep --------------------------------------------------
    hipLaunchKernelGGL(init_sintab, dim3(1), dim3(256), 0, stream, SIN);
    hipLaunchKernelGGL(prep_adj16, dim3((unsigned)((SZ16+255)/256)), dim3(256), 0, stream,
                       w3r, w3i, A3R, A3I);
    hipLaunchKernelGGL(prep_adj16, dim3((unsigned)((SZ16+255)/256)), dim3(256), 0, stream,
                       w2r, w2i, A2R, A2I);
    hipLaunchKernelGGL(prep_adj1,  dim3((unsigned)((SZ1+255)/256)),  dim3(256), 0, stream,
                       w1r, w1i, A1R, A1I);
    hipLaunchKernelGGL((compose_k<16,16,1,3,3>), dim3((unsigned)((NB*16*25+255)/256)), dim3(256),
                       0, stream, w2r, w2i, w1r, w1i, C5R, C5I);
    hipLaunchKernelGGL((compose_k<16,16,1,3,5>), dim3((unsigned)((NB*16*49+255)/256)), dim3(256),
                       0, stream, w3r, w3i, C5R, C5I, C7FR, C7FI);
    hipLaunchKernelGGL((compose_k<1,16,16,3,3>), dim3((unsigned)((NB*16*25+255)/256)), dim3(256),
                       0, stream, A1R, A1I, A2R, A2I, Q5R, Q5I);
    hipLaunchKernelGGL((compose_k<1,16,16,5,3>), dim3((unsigned)((NB*16*49+255)/256)), dim3(256),
                       0, stream, Q5R, Q5I, A3R, A3I, C7AR, C7AI);

    // ---- per-chunk pipeline --------------------------------------------
    for (int b0 = 0; b0 < NB; b0 += cbm) {
        const int cb = (NB - b0) < cbm ? (NB - b0) : cbm;

        const float* r_c    = r    + (size_t)b0 * N1 * N1;
        const float* w1r_c  = w1r  + (size_t)b0 * 144;
        const float* w1i_c  = w1i  + (size_t)b0 * 144;
        const float* w2r_c  = w2r  + (size_t)b0 * 2304;
        const float* w2i_c  = w2i  + (size_t)b0 * 2304;
        const float* w3r_c  = w3r  + (size_t)b0 * 2304;
        const float* w3i_c  = w3i  + (size_t)b0 * 2304;
        const float* a3r_c  = A3R  + (size_t)b0 * 2304;
        const float* a3i_c  = A3I  + (size_t)b0 * 2304;
        const float* a2r_c  = A2R  + (size_t)b0 * 2304;
        const float* a2i_c  = A2I  + (size_t)b0 * 2304;
        const float* a1r_c  = A1R  + (size_t)b0 * 144;
        const float* a1i_c  = A1I  + (size_t)b0 * 144;
        const float* c7fr_c = C7FR + (size_t)b0 * 784;
        const float* c7fi_c = C7FI + (size_t)b0 * 784;
        const float* c7ar_c = C7AR + (size_t)b0 * 784;
        const float* c7ai_c = C7AI + (size_t)b0 * 784;
        const float* wtr_c  = wtr  + (size_t)b0 * CH * GG;
        const float* wti_c  = wti  + (size_t)b0 * CH * GG;
        float* out_c = out + (size_t)b0 * N1 * N1;

        hipLaunchKernelGGL(dst_stage1, dim3((cb*G*N1 + 255)/256), dim3(256), 0, stream,
                           r_c, SIN, T1D, cb);
        hipLaunchKernelGGL(dst_stage2, dim3(cb*256), dim3(256), 0, stream,
                           T1D, SIN, RHAT);

        hipLaunchKernelGGL(fwd7_kernel, dim3(128, cb), dim3(256), 0, stream,
                           RHAT, c7fr_c, c7fi_c, A_RE, A_IM);
        hipLaunchKernelGGL(strip_fwd1, dim3(4, cb), dim3(256), 0, stream,
                           RHAT, w1r_c, w1i_c, S1r, S1i);
        hipLaunchKernelGGL(strip_mid, dim3(16, cb), dim3(256), 0, stream,
                           S1r, S1i, w2r_c, w2i_c, S2r, S2i);
        hipLaunchKernelGGL((strip_fin<16>), dim3(16, cb), dim3(256), 0, stream,
                           S2r, S2i, w3r_c, w3i_c, A_RE, A_IM);

        hipLaunchKernelGGL(adj7_kernel, dim3(32, cb), dim3(256), 0, stream,
                           A_RE, A_IM, wtr_c, wti_c, c7ar_c, c7ai_c, HCr, HCi, PTA);
        hipLaunchKernelGGL(strip_adj1_packed, dim3(16, cb), dim3(256), 0, stream,
                           PTA, a3r_c, a3i_c, S1r, S1i);
        hipLaunchKernelGGL(strip_mid, dim3(16, cb), dim3(256), 0, stream,
                           S1r, S1i, a2r_c, a2i_c, S2r, S2i);
        hipLaunchKernelGGL((strip_fin<1>), dim3(16, cb), dim3(256), 0, stream,
                           S2r, S2i, a1r_c, a1i_c, HCr, HCi);

        hipLaunchKernelGGL(fft_stage1, dim3(cb*N1), dim3(256), 0, stream,
                           HCr, HCi, SIN, Ur, Ui);
        hipLaunchKernelGGL(fft_stage2, dim3((cb*N1*N1 + 255)/256), dim3(256), 0, stream,
                           Ur, Ui, SIN, out_c, cb);
    }
}

// Round 9
// 962.040 us; speedup vs baseline: 1.5388x; 1.0225x over previous
//
#include <hip/hip_runtime.h>
#include <hip/hip_bf16.h>
#include <math.h>

#define NB 32
#define CH 16
#define N1 127
#define G 256
#define GG (G*G)

typedef float v2f __attribute__((ext_vector_type(2)));

// acc(lo=Re,hi=Im) += complex(x) * complex(w);  x=(xr,xi), w=(wr,wi)
#define CFMA(acc, x, w) do { \
  asm("v_pk_fma_f32 %0, %1, %2, %0 op_sel:[0,0,0] op_sel_hi:[0,1,1]" \
      : "+v"(acc) : "v"(x), "v"(w)); \
  asm("v_pk_fma_f32 %0, %1, %2, %0 op_sel:[1,1,0] op_sel_hi:[1,0,1] neg_lo:[0,1,0]" \
      : "+v"(acc) : "v"(x), "v"(w)); \
} while (0)
// acc += real(x.lo) * complex(w)
#define RFMA_LO(acc, x, w) \
  asm("v_pk_fma_f32 %0, %1, %2, %0 op_sel:[0,0,0] op_sel_hi:[0,1,1]" \
      : "+v"(acc) : "v"(x), "v"(w))
// acc += real(x.hi) * complex(w)
#define RFMA_HI(acc, x, w) \
  asm("v_pk_fma_f32 %0, %1, %2, %0 op_sel:[1,0,0] op_sel_hi:[1,1,1]" \
      : "+v"(acc) : "v"(x), "v"(w))

// ---------------------------------------------------------------------------
__global__ void init_sintab(float* __restrict__ sintab) {
    int t = threadIdx.x;
    sintab[t] = sinf(6.28318530717958647692f * (float)t / 256.0f);
}

// adj(w)[b,a,c,ky,kx] = conj(w[b,c,a,kx,ky])
__global__ __launch_bounds__(256) void prep_adj16(
    const float* __restrict__ wr, const float* __restrict__ wi,
    float* __restrict__ our, float* __restrict__ oui) {
    int idx = blockIdx.x * 256 + threadIdx.x;
    if (idx >= NB*CH*CH*9) return;
    int tap = idx % 9; int t = idx / 9;
    int c = t % CH; t /= CH;
    int a = t % CH; int b = t / CH;
    int ky = tap / 3, kx = tap % 3;
    int src = ((b*CH + c)*CH + a)*9 + kx*3 + ky;
    our[idx] = wr[src];
    oui[idx] = -wi[src];
}

__global__ __launch_bounds__(256) void prep_adj1(
    const float* __restrict__ wr, const float* __restrict__ wi,
    float* __restrict__ our, float* __restrict__ oui) {
    int idx = blockIdx.x * 256 + threadIdx.x;
    if (idx >= NB*CH*9) return;
    int tap = idx % 9; int t = idx / 9;
    int c = t % CH; int b = t / CH;
    int ky = tap / 3, kx = tap % 3;
    int src = (b*CH + c)*9 + kx*3 + ky;
    our[idx] = wr[src];
    oui[idx] = -wi[src];
}

// ---------------------------------------------------------------------------
// Kernel-tap composition: R[t] = sum_{a+b=t} P[a] Q[b]  (complex), contract CM
template<int CO, int CM, int CI, int KP, int KQ>
__global__ __launch_bounds__(256) void compose_k(
    const float* __restrict__ Pr, const float* __restrict__ Pi,
    const float* __restrict__ Qr, const float* __restrict__ Qi,
    float* __restrict__ Rr, float* __restrict__ Ri) {
    constexpr int T = KP + KQ - 1;
    int idx = blockIdx.x * 256 + threadIdx.x;
    if (idx >= NB*CO*CI*T*T) return;
    int txp = idx % T; int t = idx / T;
    int typ = t % T; t /= T;
    int ci = t % CI; t /= CI;
    int co = t % CO; int b = t / CO;
    float ar = 0.f, ai = 0.f;
    for (int m = 0; m < CM; ++m) {
        const float* pr = Pr + (((size_t)b*CO + co)*CM + m)*KP*KP;
        const float* pi = Pi + (((size_t)b*CO + co)*CM + m)*KP*KP;
        const float* qr = Qr + (((size_t)b*CM + m)*CI + ci)*KQ*KQ;
        const float* qi = Qi + (((size_t)b*CM + m)*CI + ci)*KQ*KQ;
        for (int ay = 0; ay < KP; ++ay) {
            int by = typ - ay; if (by < 0 || by >= KQ) continue;
            for (int ax = 0; ax < KP; ++ax) {
                int bx = txp - ax; if (bx < 0 || bx >= KQ) continue;
                float prr = pr[ay*KP+ax], pii = pi[ay*KP+ax];
                float qrr = qr[by*KQ+bx], qii = qi[by*KQ+bx];
                ar += prr*qrr - pii*qii;
                ai += prr*qii + pii*qrr;
            }
        }
    }
    Rr[idx] = ar; Ri[idx] = ai;
}

// ---------------------------------------------------------------------------
// DST stage 1  ((-1)^K folded into sin index)
__global__ __launch_bounds__(256) void dst_stage1(
    const float* __restrict__ r, const float* __restrict__ sintab,
    float* __restrict__ T1, int nb) {
    __shared__ float ss[256];
    ss[threadIdx.x] = sintab[threadIdx.x];
    __syncthreads();
    int idx = blockIdx.x * 256 + threadIdx.x;
    if (idx >= nb*G*N1) return;
    int kk = idx % N1;
    int t = idx / N1;
    int j1 = t & 255; int b = t >> 8;
    const float* rb = r + b * N1 * N1;
    const int j1s = (j1 + 128) & 255;
    float acc = 0.f;
    for (int K = 1; K <= N1; ++K) {
        acc = fmaf(ss[(j1s * K) & 255], rb[(K - 1) * N1 + kk], acc);
    }
    T1[idx] = acc;
}

// DST stage 2
__global__ __launch_bounds__(256) void dst_stage2(
    const float* __restrict__ T1, const float* __restrict__ sintab,
    float* __restrict__ rhat) {
    __shared__ float ss[256];
    ss[threadIdx.x] = sintab[threadIdx.x];
    __syncthreads();
    int idx = blockIdx.x * 256 + threadIdx.x;
    int j2 = idx & 255;
    int t = idx >> 8;
    int j1 = t & 255; int b = t >> 8;
    const float* t1 = T1 + ((size_t)b * G + j1) * N1;
    const int j2s = (j2 + 128) & 255;
    float acc = 0.f;
    for (int kk = 0; kk < N1; ++kk) {
        acc = fmaf(ss[(j2s * (kk + 1)) & 255], t1[kk], acc);
    }
    rhat[idx] = acc * (-4.0f / 65536.0f);
}

// ---------------------------------------------------------------------------
// Forward composed 7x7 conv: rhat (real, 1ch) -> A (16ch complex). pk_fma.
__global__ __launch_bounds__(256) void fwd7_kernel(
    const float* __restrict__ rhat,
    const float* __restrict__ w7r, const float* __restrict__ w7i, // [b][16][49]
    float* __restrict__ yr, float* __restrict__ yi) {
    __shared__ float sW[16*49*2];
    __shared__ float sIn[22*38];
    const int b = blockIdx.y;
    const int tile = blockIdx.x;            // 8 x-tiles (32) x 16 y-tiles (16)
    const int x0 = (tile & 7) * 32;
    const int y0 = (tile >> 3) * 16;
    const int tid = threadIdx.x;
    const float* wrb = w7r + (size_t)b * 784;
    const float* wib = w7i + (size_t)b * 784;
    for (int t = tid; t < 784; t += 256) { sW[2*t] = wrb[t]; sW[2*t+1] = wib[t]; }
    const float* rb = rhat + (size_t)b * GG;
    for (int t = tid; t < 22*38; t += 256) {
        int rr = t / 38, cc = t - rr * 38;
        int gy = y0 + rr - 3, gx = x0 + cc - 3;
        bool ok = ((unsigned)gy < G) & ((unsigned)gx < G);
        sIn[t] = ok ? rb[gy * G + gx] : 0.f;
    }
    __syncthreads();
    const int tx = tid & 31;
    const int ty = tid >> 5;    // 0..7
    v2f acc0[16], acc1[16];
#pragma unroll
    for (int co = 0; co < 16; ++co) { acc0[co] = (v2f){0.f,0.f}; acc1[co] = (v2f){0.f,0.f}; }
#pragma unroll
    for (int tap = 0; tap < 49; ++tap) {
        const int dy = tap / 7, dx = tap % 7;
        v2f xx;
        xx.x = sIn[(ty + dy) * 38 + tx + dx];
        xx.y = sIn[(ty + 8 + dy) * 38 + tx + dx];
#pragma unroll
        for (int co = 0; co < 16; ++co) {
            const v2f wv = *reinterpret_cast<const v2f*>(&sW[(co*49 + tap)*2]);
            RFMA_LO(acc0[co], xx, wv);
            RFMA_HI(acc1[co], xx, wv);
        }
    }
    const size_t outB = (size_t)b * 16 * GG;
#pragma unroll
    for (int co = 0; co < 16; ++co) {
        int oy0 = y0 + ty, oy1 = y0 + ty + 8, ox = x0 + tx;
        yr[outB + (size_t)co * GG + oy0 * G + ox] = acc0[co].x;
        yi[outB + (size_t)co * GG + oy0 * G + ox] = acc0[co].y;
        yr[outB + (size_t)co * GG + oy1 * G + ox] = acc1[co].x;
        yi[outB + (size_t)co * GG + oy1 * G + ox] = acc1[co].y;
    }
}

// ---------------------------------------------------------------------------
// Adjoint composed 7x7 conv with fused theta: (A .* theta) (16ch) -> HC (1ch).
// 32x32 tiles (halo 38x38, LDS 29.4KB -> 5 blocks/CU by LDS). Thread owns 4
// consecutive outputs in one row. Per (ci,dy): 5 aligned ds_read_b128 window,
// 28 pk-CFMA. LDS dbuf + async prefetch; border/interior specialization:
// only tiles at the grid edge carry bounds checks + PTA extraction.
__global__ __launch_bounds__(256) void adj7_kernel(
    const float* __restrict__ xr, const float* __restrict__ xi,
    const float* __restrict__ tr, const float* __restrict__ ti,
    const float* __restrict__ w7r, const float* __restrict__ w7i, // [b][16][49]
    float* __restrict__ or_, float* __restrict__ oi_,
    float* __restrict__ PTA) {
    constexpr int NPX = 38*38;          // 1444 staged pixels
    constexpr int NIT = 6;              // ceil(1444/256)
    __shared__ float sW[16*49*2];
    __shared__ float sIn[2][NPX*2];
    const int b = blockIdx.y;
    const int tile = blockIdx.x;        // 8 x-tiles x 8 y-tiles (32x32 each)
    const int x0 = (tile & 7) * 32;
    const int y0 = (tile >> 3) * 32;
    const int tid = threadIdx.x;
    const bool border = (x0 == 0) | (x0 == 224) | (y0 == 0) | (y0 == 224);
    const float* wrb = w7r + (size_t)b * 784;
    const float* wib = w7i + (size_t)b * 784;
    for (int t = tid; t < 784; t += 256) { sW[2*t] = wrb[t]; sW[2*t+1] = wib[t]; }

    int ppos[NIT];
#pragma unroll
    for (int i = 0; i < NIT; ++i) {
        int t = tid + i*256;
        int rr = t / 38, cc = t - rr*38;
        int gy = y0 + rr - 3, gx = x0 + cc - 3;
        bool ok = (t < NPX) & ((unsigned)gy < G) & ((unsigned)gx < G);
        ppos[i] = ok ? (gy * G + gx) : -1;
    }

    const int ty  = tid >> 3;           // 0..31: output row
    const int txi = tid & 7;            // output cols x0 + 4*txi .. +3
    v2f acc[4];
#pragma unroll
    for (int k = 0; k < 4; ++k) acc[k] = (v2f){0.f, 0.f};

    const size_t planeB = (size_t)b * 16 * GG;

    // ---- prologue: stage ci=0 into buffer 0 ----------------------------
    {
        const float* xrc = xr + planeB;
        const float* xic = xi + planeB;
        const float* trc = tr + planeB;
        const float* tic = ti + planeB;
        if (!border) {
#pragma unroll
            for (int i = 0; i < NIT; ++i) {
                int t = tid + i*256;
                if (t >= NPX) continue;
                int pp = ppos[i];
                float ar = xrc[pp], ai = xic[pp];
                float cr = trc[pp], cv = tic[pp];
                float hr = fmaf(ar, cr, -ai*cv);
                float hi = fmaf(ar, cv,  ai*cr);
                *reinterpret_cast<v2f*>(&sIn[0][2*t]) = (v2f){hr, hi};
            }
        } else {
            const size_t cbase0 = ((size_t)b * 16) * 4;
#pragma unroll
            for (int i = 0; i < NIT; ++i) {
                int t = tid + i*256;
                if (t >= NPX) continue;
                float hr = 0.f, hi = 0.f;
                int pp = ppos[i];
                if (pp >= 0) {
                    float ar = xrc[pp], ai = xic[pp];
                    float cr = trc[pp], cv = tic[pp];
                    hr = fmaf(ar, cr, -ai*cv);
                    hi = fmaf(ar, cv,  ai*cr);
                    int gy = pp >> 8, gx = pp & 255;
                    if (gy < 5)    { size_t o = ((cbase0 + 0)*5 + gy      )*256 + gx; PTA[2*o] = hr; PTA[2*o+1] = hi; }
                    if (gy >= 251) { size_t o = ((cbase0 + 1)*5 + gy - 251)*256 + gx; PTA[2*o] = hr; PTA[2*o+1] = hi; }
                    if (gx < 5)    { size_t o = ((cbase0 + 2)*5 + gx      )*256 + gy; PTA[2*o] = hr; PTA[2*o+1] = hi; }
                    if (gx >= 251) { size_t o = ((cbase0 + 3)*5 + gx - 251)*256 + gy; PTA[2*o] = hr; PTA[2*o+1] = hi; }
                }
                *reinterpret_cast<v2f*>(&sIn[0][2*t]) = (v2f){hr, hi};
            }
        }
    }
    __syncthreads();

    int cur = 0;
    for (int ci = 0; ci < 16; ++ci) {
        // ---- issue prefetch loads for ci+1 -------------------------------
        float par[NIT], pai[NIT], pcr[NIT], pcv[NIT];
        const bool havenext = (ci < 15);
        if (havenext) {
            const float* xrc = xr + planeB + (size_t)(ci+1) * GG;
            const float* xic = xi + planeB + (size_t)(ci+1) * GG;
            const float* trc = tr + planeB + (size_t)(ci+1) * GG;
            const float* tic = ti + planeB + (size_t)(ci+1) * GG;
#pragma unroll
            for (int i = 0; i < NIT; ++i) {
                int pp = ppos[i];
                if (pp >= 0) {
                    par[i] = xrc[pp]; pai[i] = xic[pp];
                    pcr[i] = trc[pp]; pcv[i] = tic[pp];
                } else { par[i] = 0.f; pai[i] = 0.f; pcr[i] = 0.f; pcv[i] = 0.f; }
            }
        }

        // ---- compute ci from sIn[cur]: window loads + pk_fma -------------
        const float* wci = &sW[ci*49*2];
        const float* bufc = &sIn[cur][0];
#pragma unroll
        for (int dy = 0; dy < 7; ++dy) {
            const float* rowp = &bufc[((ty + dy) * 38 + txi * 4) * 2];
            v2f win[10];
#pragma unroll
            for (int q = 0; q < 5; ++q) {
                const float4 vv = *reinterpret_cast<const float4*>(&rowp[q*4]);
                win[2*q]   = (v2f){vv.x, vv.y};
                win[2*q+1] = (v2f){vv.z, vv.w};
            }
#pragma unroll
            for (int dx = 0; dx < 7; ++dx) {
                const v2f wv = *reinterpret_cast<const v2f*>(&wci[(dy*7+dx)*2]);
#pragma unroll
                for (int k = 0; k < 4; ++k)
                    CFMA(acc[k], win[k+dx], wv);
            }
        }

        // ---- theta-multiply + write next buffer (+PTA if border) ---------
        if (havenext) {
            float* bufn = &sIn[cur ^ 1][0];
            if (!border) {
#pragma unroll
                for (int i = 0; i < NIT; ++i) {
                    int t = tid + i*256;
                    if (t >= NPX) continue;
                    float hr = fmaf(par[i], pcr[i], -pai[i]*pcv[i]);
                    float hi = fmaf(par[i], pcv[i],  pai[i]*pcr[i]);
                    *reinterpret_cast<v2f*>(&bufn[2*t]) = (v2f){hr, hi};
                }
            } else {
                const size_t cbase = ((size_t)b*16 + (ci+1)) * 4;
#pragma unroll
                for (int i = 0; i < NIT; ++i) {
                    int t = tid + i*256;
                    if (t >= NPX) continue;
                    float hr = 0.f, hi = 0.f;
                    int pp = ppos[i];
                    if (pp >= 0) {
                        hr = fmaf(par[i], pcr[i], -pai[i]*pcv[i]);
                        hi = fmaf(par[i], pcv[i],  pai[i]*pcr[i]);
                        int gy = pp >> 8, gx = pp & 255;
                        if (gy < 5)    { size_t o = ((cbase + 0)*5 + gy      )*256 + gx; PTA[2*o] = hr; PTA[2*o+1] = hi; }
                        if (gy >= 251) { size_t o = ((cbase + 1)*5 + gy - 251)*256 + gx; PTA[2*o] = hr; PTA[2*o+1] = hi; }
                        if (gx < 5)    { size_t o = ((cbase + 2)*5 + gx      )*256 + gy; PTA[2*o] = hr; PTA[2*o+1] = hi; }
                        if (gx >= 251) { size_t o = ((cbase + 3)*5 + gx - 251)*256 + gy; PTA[2*o] = hr; PTA[2*o+1] = hi; }
                    }
                    *reinterpret_cast<v2f*>(&bufn[2*t]) = (v2f){hr, hi};
                }
            }
        }
        __syncthreads();
        cur ^= 1;
    }

    const size_t outB = (size_t)b * GG;
    const int oy = y0 + ty, ox = x0 + txi * 4;
    float4 r0 = make_float4(acc[0].x, acc[1].x, acc[2].x, acc[3].x);
    float4 i0 = make_float4(acc[0].y, acc[1].y, acc[2].y, acc[3].y);
    *reinterpret_cast<float4*>(&or_[outB + oy*G + ox]) = r0;
    *reinterpret_cast<float4*>(&oi_[outB + oy*G + ox]) = i0;
}

// ---------------------------------------------------------------------------
// Strip machinery. strip s: 0=TOP, 1=BOT, 2=LEF, 3=RIG. [b][ch][s][u:4][v:256].
__device__ __forceinline__ size_t sidx(int b, int ch, int s, int u, int v) {
    return ((((size_t)b*CH + ch)*4 + s)*4 + u)*256 + v;
}
__device__ __forceinline__ void spos(int s, int u, int v, int& y, int& x) {
    y = (s == 0) ? u : (s == 1) ? 252 + u : v;
    x = (s == 2) ? u : (s == 3) ? 252 + u : v;
}

// stage 1 fwd: conv1 (w1, 1->16, real rhat) exact, all u in [0,4)
__global__ __launch_bounds__(256) void strip_fwd1(
    const float* __restrict__ rhat,
    const float* __restrict__ w1r_, const float* __restrict__ w1i_, // [b][16][9]
    float* __restrict__ S1r, float* __restrict__ S1i) {
    __shared__ float sW[16*9*2];
    const int s = blockIdx.x, b = blockIdx.y;
    for (int t = threadIdx.x; t < 144; t += 256) {
        sW[2*t] = w1r_[(size_t)b*144 + t]; sW[2*t+1] = w1i_[(size_t)b*144 + t];
    }
    __syncthreads();
    const int v = threadIdx.x;
    const float* rb = rhat + (size_t)b * GG;
    for (int u = 0; u < 4; ++u) {
        int y, x; spos(s, u, v, y, x);
        float xv[9];
#pragma unroll
        for (int dy = -1; dy <= 1; ++dy)
#pragma unroll
            for (int dx = -1; dx <= 1; ++dx) {
                int gy = y + dy, gx = x + dx;
                bool ok = ((unsigned)gy < G) & ((unsigned)gx < G);
                xv[(dy+1)*3 + dx+1] = ok ? rb[gy*G+gx] : 0.f;
            }
#pragma unroll
        for (int co = 0; co < 16; ++co) {
            float ar = 0.f, ai = 0.f;
#pragma unroll
            for (int tap = 0; tap < 9; ++tap) {
                ar = fmaf(xv[tap], sW[(co*9+tap)*2], ar);
                ai = fmaf(xv[tap], sW[(co*9+tap)*2+1], ai);
            }
            S1r[sidx(b, co, s, u, v)] = ar;
            S1i[sidx(b, co, s, u, v)] = ai;
        }
    }
}

// stage 1 adj (packed): a3-conv on packed theta.*A bands. u in [0,4). pk_fma.
__global__ __launch_bounds__(256) void strip_adj1_packed(
    const float* __restrict__ PTA,   // [b][ci][4][5][256][2]
    const float* __restrict__ wr_, const float* __restrict__ wi_, // [b][16][16][9]
    float* __restrict__ S1r, float* __restrict__ S1i) {
    __shared__ float sW[16*16*9*2];
    const int s = blockIdx.x >> 2, vt = blockIdx.x & 3, b = blockIdx.y;
    for (int t = threadIdx.x; t < 2304; t += 256) {
        sW[2*t] = wr_[(size_t)b*2304 + t]; sW[2*t+1] = wi_[(size_t)b*2304 + t];
    }
    __syncthreads();
    const int v = vt * 64 + (threadIdx.x & 63);
    const int u = threadIdx.x >> 6;           // 0..3
    const int off = (s == 1 || s == 3) ? 1 : 0;
    v2f acc[16];
#pragma unroll
    for (int co = 0; co < 16; ++co) acc[co] = (v2f){0.f, 0.f};
    for (int ci = 0; ci < 16; ++ci) {
        const float* base = PTA + ((((size_t)b*16 + ci)*4 + s)*5) * 512;
        v2f n2[9];
#pragma unroll
        for (int dy = -1; dy <= 1; ++dy)
#pragma unroll
            for (int dx = -1; dx <= 1; ++dx) {
                int pu = (s < 2) ? (u + off + dy) : (u + off + dx);
                int vp = (s < 2) ? (v + dx) : (v + dy);
                v2f val = (v2f){0.f, 0.f};
                if (((unsigned)pu < 5u) & ((unsigned)vp < 256u))
                    val = *reinterpret_cast<const v2f*>(&base[(pu*256 + vp)*2]);
                n2[(dy+1)*3+dx+1] = val;
            }
#pragma unroll
        for (int co = 0; co < 16; ++co)
#pragma unroll
            for (int tap = 0; tap < 9; ++tap) {
                const v2f wv = *reinterpret_cast<const v2f*>(&sW[((co*16+ci)*9+tap)*2]);
                CFMA(acc[co], n2[tap], wv);
            }
    }
#pragma unroll
    for (int co = 0; co < 16; ++co) {
        S1r[sidx(b, co, s, u, v)] = acc[co].x;
        S1i[sidx(b, co, s, u, v)] = acc[co].y;
    }
}

// stage 2: 16->16 conv strips->strips, u in [u0, u0+3). grid (16, cb). pk_fma.
__global__ __launch_bounds__(256) void strip_mid(
    const float* __restrict__ Ar, const float* __restrict__ Ai,
    const float* __restrict__ wr_, const float* __restrict__ wi_, // [b][16][16][9]
    float* __restrict__ Br, float* __restrict__ Bi) {
    __shared__ float sW[16*16*9*2];
    const int s = blockIdx.x >> 2, vt = blockIdx.x & 3, b = blockIdx.y;
    for (int t = threadIdx.x; t < 2304; t += 256) {
        sW[2*t] = wr_[(size_t)b*2304 + t]; sW[2*t+1] = wi_[(size_t)b*2304 + t];
    }
    __syncthreads();
    const int v = vt * 64 + (threadIdx.x & 63);
    const int uslot = threadIdx.x >> 6;
    if (uslot >= 3) return;
    const int u0 = (s == 1 || s == 3) ? 1 : 0;
    const int u = u0 + uslot;
    int y, x; spos(s, u, v, y, x);
    v2f acc[16];
#pragma unroll
    for (int co = 0; co < 16; ++co) acc[co] = (v2f){0.f, 0.f};
    for (int ci = 0; ci < 16; ++ci) {
        v2f n2[9];
#pragma unroll
        for (int dy = -1; dy <= 1; ++dy)
#pragma unroll
            for (int dx = -1; dx <= 1; ++dx) {
                int gy = y + dy, gx = x + dx;
                v2f val = (v2f){0.f, 0.f};
                if (((unsigned)gy < G) & ((unsigned)gx < G)) {
                    int up = (s < 2) ? u + dy : u + dx;
                    int vp = (s < 2) ? v + dx : v + dy;
                    size_t ix = sidx(b, ci, s, up, vp);
                    val.x = Ar[ix]; val.y = Ai[ix];
                }
                n2[(dy+1)*3+dx+1] = val;
            }
#pragma unroll
        for (int co = 0; co < 16; ++co)
#pragma unroll
            for (int tap = 0; tap < 9; ++tap) {
                const v2f wv = *reinterpret_cast<const v2f*>(&sW[((co*16+ci)*9+tap)*2]);
                CFMA(acc[co], n2[tap], wv);
            }
    }
#pragma unroll
    for (int co = 0; co < 16; ++co) {
        Br[sidx(b, co, s, u, v)] = acc[co].x;
        Bi[sidx(b, co, s, u, v)] = acc[co].y;
    }
}

// stage 3: COUT ch from strips -> overwrite band in planes, u in [u0,u0+2). pk_fma.
template<int COUT>
__global__ __launch_bounds__(256) void strip_fin(
    const float* __restrict__ Ar, const float* __restrict__ Ai,
    const float* __restrict__ wr_, const float* __restrict__ wi_, // [b][COUT][16][9]
    float* __restrict__ Or, float* __restrict__ Oi) {
    __shared__ float sW[COUT*16*9*2];
    const int s = blockIdx.x >> 2, vt = blockIdx.x & 3, b = blockIdx.y;
    for (int t = threadIdx.x; t < COUT*144; t += 256) {
        sW[2*t] = wr_[(size_t)b*COUT*144 + t]; sW[2*t+1] = wi_[(size_t)b*COUT*144 + t];
    }
    __syncthreads();
    const int v = vt * 64 + (threadIdx.x & 63);
    const int uslot = threadIdx.x >> 6;
    if (uslot >= 2) return;
    const int u0 = (s == 1 || s == 3) ? 2 : 0;
    const int u = u0 + uslot;
    int y, x; spos(s, u, v, y, x);
    v2f acc[COUT];
#pragma unroll
    for (int co = 0; co < COUT; ++co) acc[co] = (v2f){0.f, 0.f};
    for (int ci = 0; ci < 16; ++ci) {
        v2f n2[9];
#pragma unroll
        for (int dy = -1; dy <= 1; ++dy)
#pragma unroll
            for (int dx = -1; dx <= 1; ++dx) {
                int gy = y + dy, gx = x + dx;
                v2f val = (v2f){0.f, 0.f};
                if (((unsigned)gy < G) & ((unsigned)gx < G)) {
                    int up = (s < 2) ? u + dy : u + dx;
                    int vp = (s < 2) ? v + dx : v + dy;
                    size_t ix = sidx(b, ci, s, up, vp);
                    val.x = Ar[ix]; val.y = Ai[ix];
                }
                n2[(dy+1)*3+dx+1] = val;
            }
#pragma unroll
        for (int co = 0; co < COUT; ++co)
#pragma unroll
            for (int tap = 0; tap < 9; ++tap) {
                const v2f wv = *reinterpret_cast<const v2f*>(&sW[((co*16+ci)*9+tap)*2]);
                CFMA(acc[co], n2[tap], wv);
            }
    }
#pragma unroll
    for (int co = 0; co < COUT; ++co) {
        Or[((size_t)b*COUT + co)*GG + y*G + x] = acc[co].x;
        Oi[((size_t)b*COUT + co)*GG + y*G + x] = acc[co].y;
    }
}

// ---------------------------------------------------------------------------
__global__ __launch_bounds__(256) void fft_stage1(
    const float* __restrict__ hr, const float* __restrict__ hi,
    const float* __restrict__ sintab,
    float* __restrict__ Ur, float* __restrict__ Ui) {
    __shared__ float ss[256];
    ss[threadIdx.x] = sintab[threadIdx.x];
    __syncthreads();
    int idx = blockIdx.x * 256 + threadIdx.x;
    int j2 = idx & 255;
    int t = idx >> 8;
    int k1 = t % N1; int b = t / N1;
    const float* hrb = hr + (size_t)b * GG;
    const float* hib = hi + (size_t)b * GG;
    float ur = 0.f, ui = 0.f;
    for (int j1 = 0; j1 < G; ++j1) {
        int ph = (k1 * j1) & 255;
        float s = ss[ph], c = ss[(ph + 64) & 255];
        float xr = hrb[j1 * G + j2], xi = hib[j1 * G + j2];
        ur += xr * c + xi * s;
        ui += xi * c - xr * s;
    }
    Ur[idx] = ur; Ui[idx] = ui;
}

__global__ __launch_bounds__(256) void fft_stage2(
    const float* __restrict__ Ur, const float* __restrict__ Ui,
    const float* __restrict__ sintab, float* __restrict__ out, int nb) {
    __shared__ float ss[256];
    ss[threadIdx.x] = sintab[threadIdx.x];
    __syncthreads();
    int idx = blockIdx.x * 256 + threadIdx.x;
    if (idx >= nb * N1 * N1) return;
    int k2 = idx % N1;
    int t = idx / N1;
    int k1 = t % N1; int b = t / N1;
    const float* urb = Ur + ((size_t)b * N1 + k1) * G;
    const float* uib = Ui + ((size_t)b * N1 + k1) * G;
    float acc = 0.f;
    for (int j2 = 0; j2 < G; ++j2) {
        int ph = (k2 * j2) & 255;
        float s = ss[ph], c = ss[(ph + 64) & 255];
        acc += urb[j2] * c + uib[j2] * s;
    }
    out[idx] = ((k1 + k2) & 1) ? -acc : acc;
}

// ---------------------------------------------------------------------------
extern "C" void kernel_launch(void* const* d_in, const int* in_sizes, int n_in,
                              void* d_out, int out_size, void* d_ws, size_t ws_size,
                              hipStream_t stream) {
    const float* r   = (const float*)d_in[0];
    const float* w1r = (const float*)d_in[1];
    const float* w1i = (const float*)d_in[2];
    const float* w2r = (const float*)d_in[3];
    const float* w2i = (const float*)d_in[4];
    const float* w3r = (const float*)d_in[5];
    const float* w3i = (const float*)d_in[6];
    const float* wtr = (const float*)d_in[7];
    const float* wti = (const float*)d_in[8];
    float* out = (float*)d_out;

    float* ws = (float*)d_ws;
    const size_t g = (size_t)GG;

    // ---- fixed region ---------------------------------------------------
    const size_t SZ16 = (size_t)NB*CH*CH*9;   // 73728
    const size_t SZ1  = (size_t)NB*CH*9;      // 4608
    const size_t SZ5  = (size_t)NB*16*25;
    const size_t SZ7  = (size_t)NB*16*49;
    float* p = ws;
    float* SIN  = p; p += 1024;
    float* A3R = p; p += SZ16;  float* A3I = p; p += SZ16;
    float* A2R = p; p += SZ16;  float* A2I = p; p += SZ16;
    float* A1R = p; p += SZ1;   float* A1I = p; p += SZ1;
    float* C5R = p; p += SZ5;   float* C5I = p; p += SZ5;
    float* C7FR = p; p += SZ7;  float* C7FI = p; p += SZ7;
    float* Q5R = p; p += SZ5;   float* Q5I = p; p += SZ5;
    float* C7AR = p; p += SZ7;  float* C7AI = p; p += SZ7;
    const size_t extraFloats = (size_t)(p - ws);

    // ---- adaptive chunking ---------------------------------------------
    const size_t sampFloats = 32*g + g + g/2 + 2*g + 2*g + 2*g + g + g/2 + 5*g;
    size_t availFloats = ws_size / 4;
    long long usable = (long long)availFloats - (long long)extraFloats;
    int cbm = 1;
    if (usable > 0) {
        long long c = usable / (long long)sampFloats;
        cbm = (int)(c < 1 ? 1 : (c > NB ? NB : c));
    }

    float* base = ws + extraFloats;
    float* A_RE = base;
    float* A_IM = A_RE + (size_t)cbm*16*g;
    float* RHAT = A_IM + (size_t)cbm*16*g;
    float* T1D  = RHAT + (size_t)cbm*g;
    float* S1r  = T1D + (size_t)cbm*(g/2);
    float* S1i  = S1r + (size_t)cbm*g;
    float* S2r  = S1i + (size_t)cbm*g;
    float* S2i  = S2r + (size_t)cbm*g;
    float* HCr  = S2i + (size_t)cbm*g;
    float* HCi  = HCr + (size_t)cbm*g;
    float* Ur   = HCi + (size_t)cbm*g;
    float* Ui   = Ur + (size_t)cbm*(g/2);
    float* PTA  = Ui + (size_t)cbm*(g/2);      // [cb][16][4][5][256][2]

    // ---- one-time prep --------------------------------------------------
    hipLaunchKernelGGL(init_sintab, dim3(1), dim3(256), 0, stream, SIN);
    hipLaunchKernelGGL(prep_adj16, dim3((unsigned)((SZ16+255)/256)), dim3(256), 0, stream,
                       w3r, w3i, A3R, A3I);
    hipLaunchKernelGGL(prep_adj16, dim3((unsigned)((SZ16+255)/256)), dim3(256), 0, stream,
                       w2r, w2i, A2R, A2I);
    hipLaunchKernelGGL(prep_adj1,  dim3((unsigned)((SZ1+255)/256)),  dim3(256), 0, stream,
                       w1r, w1i, A1R, A1I);
    hipLaunchKernelGGL((compose_k<16,16,1,3,3>), dim3((unsigned)((NB*16*25+255)/256)), dim3(256),
                       0, stream, w2r, w2i, w1r, w1i, C5R, C5I);
    hipLaunchKernelGGL((compose_k<16,16,1,3,5>), dim3((unsigned)((NB*16*49+255)/256)), dim3(256),
                       0, stream, w3r, w3i, C5R, C5I, C7FR, C7FI);
    hipLaunchKernelGGL((compose_k<1,16,16,3,3>), dim3((unsigned)((NB*16*25+255)/256)), dim3(256),
                       0, stream, A1R, A1I, A2R, A2I, Q5R, Q5I);
    hipLaunchKernelGGL((compose_k<1,16,16,5,3>), dim3((unsigned)((NB*16*49+255)/256)), dim3(256),
                       0, stream, Q5R, Q5I, A3R, A3I, C7AR, C7AI);

    // ---- per-chunk pipeline --------------------------------------------
    for (int b0 = 0; b0 < NB; b0 += cbm) {
        const int cb = (NB - b0) < cbm ? (NB - b0) : cbm;

        const float* r_c    = r    + (size_t)b0 * N1 * N1;
        const float* w1r_c  = w1r  + (size_t)b0 * 144;
        const float* w1i_c  = w1i  + (size_t)b0 * 144;
        const float* w2r_c  = w2r  + (size_t)b0 * 2304;
        const float* w2i_c  = w2i  + (size_t)b0 * 2304;
        const float* w3r_c  = w3r  + (size_t)b0 * 2304;
        const float* w3i_c  = w3i  + (size_t)b0 * 2304;
        const float* a3r_c  = A3R  + (size_t)b0 * 2304;
        const float* a3i_c  = A3I  + (size_t)b0 * 2304;
        const float* a2r_c  = A2R  + (size_t)b0 * 2304;
        const float* a2i_c  = A2I  + (size_t)b0 * 2304;
        const float* a1r_c  = A1R  + (size_t)b0 * 144;
        const float* a1i_c  = A1I  + (size_t)b0 * 144;
        const float* c7fr_c = C7FR + (size_t)b0 * 784;
        const float* c7fi_c = C7FI + (size_t)b0 * 784;
        const float* c7ar_c = C7AR + (size_t)b0 * 784;
        const float* c7ai_c = C7AI + (size_t)b0 * 784;
        const float* wtr_c  = wtr  + (size_t)b0 * CH * GG;
        const float* wti_c  = wti  + (size_t)b0 * CH * GG;
        float* out_c = out + (size_t)b0 * N1 * N1;

        hipLaunchKernelGGL(dst_stage1, dim3((cb*G*N1 + 255)/256), dim3(256), 0, stream,
                           r_c, SIN, T1D, cb);
        hipLaunchKernelGGL(dst_stage2, dim3(cb*256), dim3(256), 0, stream,
                           T1D, SIN, RHAT);

        hipLaunchKernelGGL(fwd7_kernel, dim3(128, cb), dim3(256), 0, stream,
                           RHAT, c7fr_c, c7fi_c, A_RE, A_IM);
        hipLaunchKernelGGL(strip_fwd1, dim3(4, cb), dim3(256), 0, stream,
                           RHAT, w1r_c, w1i_c, S1r, S1i);
        hipLaunchKernelGGL(strip_mid, dim3(16, cb), dim3(256), 0, stream,
                           S1r, S1i, w2r_c, w2i_c, S2r, S2i);
        hipLaunchKernelGGL((strip_fin<16>), dim3(16, cb), dim3(256), 0, stream,
                           S2r, S2i, w3r_c, w3i_c, A_RE, A_IM);

        hipLaunchKernelGGL(adj7_kernel, dim3(64, cb), dim3(256), 0, stream,
                           A_RE, A_IM, wtr_c, wti_c, c7ar_c, c7ai_c, HCr, HCi, PTA);
        hipLaunchKernelGGL(strip_adj1_packed, dim3(16, cb), dim3(256), 0, stream,
                           PTA, a3r_c, a3i_c, S1r, S1i);
        hipLaunchKernelGGL(strip_mid, dim3(16, cb), dim3(256), 0, stream,
                           S1r, S1i, a2r_c, a2i_c, S2r, S2i);
        hipLaunchKernelGGL((strip_fin<1>), dim3(16, cb), dim3(256), 0, stream,
                           S2r, S2i, a1r_c, a1i_c, HCr, HCi);

        hipLaunchKernelGGL(fft_stage1, dim3(cb*N1), dim3(256), 0, stream,
                           HCr, HCi, SIN, Ur, Ui);
        hipLaunchKernelGGL(fft_stage2, dim3((cb*N1*N1 + 255)/256), dim3(256), 0, stream,
                           Ur, Ui, SIN, out_c, cb);
    }
}